// Round 6
// baseline (1643.930 us; speedup 1.0000x reference)
//
#include <hip/hip_runtime.h>
#include <hip/hip_bf16.h>

using short8 = __attribute__((ext_vector_type(8))) short;
using f32x4  = __attribute__((ext_vector_type(4))) float;
typedef unsigned int u32;

static constexpr int NN = 65536;   // nodes
static constexpr int F  = 256;     // feat dim
static constexpr int KE = 8;       // experts
static constexpr int KD = KE * F;  // 2048 = GEMM inner dim
static constexpr int NB = 256;     // coarse buckets (row>>8)
static constexpr int EPB = 8192;   // edges per bucket_scatter block
static constexpr int BCAP = 12288; // bucket LDS capacity (avg 8192, +45 sigma margin)

__device__ __forceinline__ short f2bf(float f) {
    union { __hip_bfloat16 h; short s; } u;
    u.h = __float2bfloat16(f);
    return u.s;
}
__device__ __forceinline__ float bf_lo(unsigned u) { return __uint_as_float(u << 16); }
__device__ __forceinline__ float bf_hi(unsigned u) { return __uint_as_float(u & 0xFFFF0000u); }

// async 16B global->LDS (dest = wave-uniform base + lane*16, HW-enforced)
__device__ __forceinline__ void gld_lds16(void* lds, const void* g) {
    __builtin_amdgcn_global_load_lds((const __attribute__((address_space(1))) u32*)g,
                                     (__attribute__((address_space(3))) u32*)lds, 16, 0, 0);
}

// ---------- x f32 -> xb bf16 (halves gather read traffic)
__global__ __launch_bounds__(256)
void conv_x(const float* __restrict__ x, short* __restrict__ xb) {
    const size_t i = ((size_t)blockIdx.x * 256 + threadIdx.x) * 8;
    const float4 a = *(const float4*)(x + i);
    const float4 b = *(const float4*)(x + i + 4);
    short8 p;
    p[0]=f2bf(a.x); p[1]=f2bf(a.y); p[2]=f2bf(a.z); p[3]=f2bf(a.w);
    p[4]=f2bf(b.x); p[5]=f2bf(b.y); p[6]=f2bf(b.z); p[7]=f2bf(b.w);
    *(short8*)(xb + i) = p;
}

// ---------- W [8][256][256] f32 -> WbT [256][2048] bf16, WbT[o][e*256+i] = W[e][i][o]
__global__ void prep_w(const float* __restrict__ W, short* __restrict__ WbT) {
    __shared__ float tile[64][65];
    const int e  = blockIdx.z;
    const int i0 = blockIdx.x * 64;
    const int o0 = blockIdx.y * 64;
    const int c  = threadIdx.x & 63;
    const int r4 = threadIdx.x >> 6;
    for (int rr = r4; rr < 64; rr += 4)
        tile[rr][c] = W[((size_t)e * F + i0 + rr) * F + o0 + c];
    __syncthreads();
    for (int rr = r4; rr < 64; rr += 4)
        WbT[(size_t)(o0 + rr) * KD + e * F + i0 + c] = f2bf(tile[c][rr]);
}

// ---------- P1: coarse-bucket histogram (256 buckets of 256 rows)
__global__ __launch_bounds__(256)
void bucket_hist(const int* __restrict__ rows, int* __restrict__ bcount, int E) {
    __shared__ int h[NB];
    const int tid = threadIdx.x;
    h[tid] = 0;
    __syncthreads();
    const int base = blockIdx.x * EPB;
    const int lim  = min(EPB, E - base);
    for (int i = tid; i < lim; i += 256)
        atomicAdd(&h[rows[base + i] >> 8], 1);
    __syncthreads();
    if (h[tid]) atomicAdd(&bcount[tid], h[tid]);
}

// ---------- P2: 256-wide exclusive scan -> bucket bases + cursors
__global__ __launch_bounds__(256)
void bucket_scan(const int* __restrict__ bcount, int* __restrict__ bbase,
                 int* __restrict__ bcursor) {
    __shared__ int s[NB];
    const int tid = threadIdx.x;
    const int c = bcount[tid];
    s[tid] = c;
    __syncthreads();
    for (int off = 1; off < NB; off <<= 1) {
        int v = (tid >= off) ? s[tid - off] : 0;
        __syncthreads();
        s[tid] += v;
        __syncthreads();
    }
    const int excl = s[tid] - c;
    bbase[tid]   = excl;
    bcursor[tid] = excl;
    if (tid == NB - 1) bbase[NB] = s[tid];
}

// ---------- P3: scatter edges into coarse buckets (L2-merged contiguous runs)
__global__ __launch_bounds__(256)
void bucket_scatter(const int* __restrict__ rows, const int* __restrict__ cols,
                    const float* __restrict__ vals, int* __restrict__ bcursor,
                    int2* __restrict__ tmp, int E) {
    __shared__ int h[NB], wb[NB];
    const int tid = threadIdx.x;
    h[tid] = 0;
    __syncthreads();
    const int base = blockIdx.x * EPB;
    const int lim  = min(EPB, E - base);
    for (int i = tid; i < lim; i += 256)
        atomicAdd(&h[rows[base + i] >> 8], 1);
    __syncthreads();
    const int c = h[tid];
    wb[tid] = c ? atomicAdd(&bcursor[tid], c) : 0;
    h[tid] = 0;
    __syncthreads();
    for (int i = tid; i < lim; i += 256) {
        const int r  = rows[base + i];
        const int bk = r >> 8;
        const int rank = atomicAdd(&h[bk], 1);
        tmp[wb[bk] + rank] = make_int2(((r & 255) << 16) | cols[base + i],
                                       __float_as_int(vals[base + i]));
    }
}

// ---------- P4: one block per bucket: row-CSR + coarse col-sort (8 col-range
// passes of 4MB-of-xb each) so gather sweeps L2-sized col windows.
__global__ __launch_bounds__(256)
void bucket_to_csr(const int* __restrict__ bbase, int2* __restrict__ tmp,
                   int* __restrict__ offsets) {
    __shared__ int2 buf[BCAP];          // 96 KB
    __shared__ int h[NB], off[NB];
    const int tid = threadIdx.x;
    const int k   = blockIdx.x;
    const int beg = bbase[k];
    const int end = bbase[k + 1];
    const int n   = end - beg;
    h[tid] = 0;
    __syncthreads();
    for (int i = tid; i < n; i += 256) {
        const int2 e = tmp[beg + i];
        if (i < BCAP) buf[i] = e;
        atomicAdd(&h[e.x >> 16], 1);
    }
    __syncthreads();
    const int c = h[tid];
    off[tid] = c;
    __syncthreads();
    for (int o = 1; o < NB; o <<= 1) {
        int v = (tid >= o) ? off[tid - o] : 0;
        __syncthreads();
        off[tid] += v;
        __syncthreads();
    }
    const int excl = off[tid] - c;
    offsets[k * NB + tid] = beg + excl;
    if (k == NB - 1 && tid == NB - 1) offsets[NN] = end;
    h[tid] = excl;                      // reuse as within-bucket cursor
    __syncthreads();
    for (int p = 0; p < 8; ++p) {       // col-range passes: cr = col>>13
        for (int i = tid; i < n; i += 256) {
            const int2 e = (i < BCAP) ? buf[i] : tmp[beg + i];
            if (((e.x >> 13) & 7) == p) {
                const int r = e.x >> 16;
                const int pos = atomicAdd(&h[r], 1);
                tmp[beg + pos] = make_int2(e.x & 0xFFFF, e.y);
            }
        }
        __syncthreads();
    }
}

// ---------- gather: per-row segmented accumulate (bf16 x), hi written f32 into d_out
__global__ __launch_bounds__(256)
void gather_rows(const short* __restrict__ xb, const int2* __restrict__ scv,
                 const int* __restrict__ offsets, float* __restrict__ hi) {
    const int lane = threadIdx.x & 63;
    int row = (blockIdx.x << 2) + (threadIdx.x >> 6);
    row = __builtin_amdgcn_readfirstlane(row);
    const int beg = offsets[row];
    const int end = offsets[row + 1];
    float4 acc = {0.f, 0.f, 0.f, 0.f};
    int j = beg;
    for (; j + 8 <= end; j += 8) {
        int2 cc[8], rr[8];
        #pragma unroll
        for (int q = 0; q < 8; ++q) cc[q] = scv[j + q];
        #pragma unroll
        for (int q = 0; q < 8; ++q)
            rr[q] = ((const int2*)(xb + (size_t)cc[q].x * F))[lane];
        #pragma unroll
        for (int q = 0; q < 8; ++q) {
            const float v = __int_as_float(cc[q].y);
            acc.x += v * bf_lo(rr[q].x); acc.y += v * bf_hi(rr[q].x);
            acc.z += v * bf_lo(rr[q].y); acc.w += v * bf_hi(rr[q].y);
        }
    }
    for (; j + 4 <= end; j += 4) {
        int2 cc[4], rr[4];
        #pragma unroll
        for (int q = 0; q < 4; ++q) cc[q] = scv[j + q];
        #pragma unroll
        for (int q = 0; q < 4; ++q)
            rr[q] = ((const int2*)(xb + (size_t)cc[q].x * F))[lane];
        #pragma unroll
        for (int q = 0; q < 4; ++q) {
            const float v = __int_as_float(cc[q].y);
            acc.x += v * bf_lo(rr[q].x); acc.y += v * bf_hi(rr[q].x);
            acc.z += v * bf_lo(rr[q].y); acc.w += v * bf_hi(rr[q].y);
        }
    }
    for (; j < end; ++j) {
        const int2 c0 = scv[j];
        const int2 r0 = ((const int2*)(xb + (size_t)c0.x * F))[lane];
        const float v0 = __int_as_float(c0.y);
        acc.x += v0*bf_lo(r0.x); acc.y += v0*bf_hi(r0.x);
        acc.z += v0*bf_lo(r0.y); acc.w += v0*bf_hi(r0.y);
    }
    ((float4*)(hi + (size_t)row * F))[lane] = acc;
}

// ---------- GEMM: out[n,o] = sum_e z[n,e] * (hi[n,:] @ W[e]) + x[n,o]
// A resident in LDS (read ONCE per i0 into regs, reused across 8 experts);
// B double-buffered via global_load_lds; z folded at every (e,i0) boundary.
#define BM 128
__global__ __launch_bounds__(512, 1)
void moe_gemm(const float* __restrict__ hi, const float* __restrict__ z,
              const short* __restrict__ WbT, const float* __restrict__ x,
              float* __restrict__ out) {
    __shared__ short A_lds[BM * F];          // 64 KB, XOR-swizzled
    __shared__ short B_lds[2][256 * 64];     // 2 x 32 KB
    __shared__ float z_lds[BM * KE];         // 4 KB
    const int tid  = threadIdx.x;
    const int lane = tid & 63;
    const int w    = tid >> 6;
    const int wr   = w >> 2;
    const int wc   = w & 3;
    const int row0 = blockIdx.x * BM;

    // step s <-> (i0b = s>>3, e = s&7); chunk bytes: e*512 + i0b*128 within WbT row
    auto stageB = [&](int s, int buf) {
        const int kb0 = (s & 7) * 512 + (s >> 3) * 128;
        #pragma unroll
        for (int q = 0; q < 4; ++q) {
            const int d     = (tid + q * 512) * 16;
            const int o     = d >> 7;
            const int kbyte = d & 127;
            const char* src = (const char*)WbT + (size_t)o * (KD * 2) + kb0
                              + (kbyte ^ ((o & 7) << 4));
            gld_lds16((char*)&B_lds[buf][0] + (w * 64 + q * 512) * 16, src);
        }
    };

    for (int idx = tid; idx < BM * KE; idx += 512)
        z_lds[idx] = z[(size_t)row0 * KE + idx];
    stageB(0, 0);
    {
        const int m0 = tid >> 5;
        const int c8 = tid & 31;
        for (int p = 0; p < BM / 16; ++p) {
            const int m = p * 16 + m0;
            const float4* src = (const float4*)(hi + (size_t)(row0 + m) * F + c8 * 8);
            const float4 a = src[0], b = src[1];
            short8 pk;
            pk[0]=f2bf(a.x); pk[1]=f2bf(a.y); pk[2]=f2bf(a.z); pk[3]=f2bf(a.w);
            pk[4]=f2bf(b.x); pk[5]=f2bf(b.y); pk[6]=f2bf(b.z); pk[7]=f2bf(b.w);
            const int idx = (m * F + c8 * 8) ^ ((m & 7) << 3);
            *(short8*)&A_lds[idx] = pk;
        }
    }
    __syncthreads();

    f32x4 acc_t[4][4];
    #pragma unroll
    for (int mi = 0; mi < 4; ++mi)
        #pragma unroll
        for (int ni = 0; ni < 4; ++ni)
            acc_t[mi][ni] = (f32x4){0.f, 0.f, 0.f, 0.f};

    const int lr    = lane & 15;
    const int krow  = 8 * (lane >> 4);
    const int rbase = (lane >> 4) * 4;

    for (int i0b = 0; i0b < 4; ++i0b) {
        const int i0 = i0b * 64;
        short8 af[4][2];                     // A fragments: read once, reuse 8 experts
        #pragma unroll
        for (int ks = 0; ks < 2; ++ks)
            #pragma unroll
            for (int mi = 0; mi < 4; ++mi) {
                const int m = wr * 64 + mi * 16 + lr;
                af[mi][ks] = *(const short8*)&A_lds[(m * F + i0 + ks * 32 + krow) ^ ((m & 7) << 3)];
            }
        for (int e = 0; e < KE; ++e) {
            const int s   = i0b * 8 + e;
            const int cur = s & 1;
            if (s + 1 < 32) stageB(s + 1, cur ^ 1);

            short8 bf[4][2];
            #pragma unroll
            for (int ks = 0; ks < 2; ++ks)
                #pragma unroll
                for (int ni = 0; ni < 4; ++ni) {
                    const int o = wc * 64 + ni * 16 + lr;
                    bf[ni][ks] = *(const short8*)&B_lds[cur][(o * 64 + ks * 32 + krow) ^ ((o & 7) << 3)];
                }
            f32x4 acc_e[4][4];
            #pragma unroll
            for (int mi = 0; mi < 4; ++mi)
                #pragma unroll
                for (int ni = 0; ni < 4; ++ni)
                    acc_e[mi][ni] = (f32x4){0.f, 0.f, 0.f, 0.f};
            #pragma unroll
            for (int ks = 0; ks < 2; ++ks)
                #pragma unroll
                for (int mi = 0; mi < 4; ++mi)
                    #pragma unroll
                    for (int ni = 0; ni < 4; ++ni)
                        acc_e[mi][ni] = __builtin_amdgcn_mfma_f32_16x16x32_bf16(
                            af[mi][ks], bf[ni][ks], acc_e[mi][ni], 0, 0, 0);
            #pragma unroll
            for (int mi = 0; mi < 4; ++mi) {
                float zv[4];
                #pragma unroll
                for (int r = 0; r < 4; ++r)
                    zv[r] = z_lds[(wr * 64 + mi * 16 + rbase + r) * KE + e];
                #pragma unroll
                for (int ni = 0; ni < 4; ++ni)
                    #pragma unroll
                    for (int r = 0; r < 4; ++r)
                        acc_t[mi][ni][r] += zv[r] * acc_e[mi][ni][r];
            }
            __syncthreads();
        }
    }

    #pragma unroll
    for (int mi = 0; mi < 4; ++mi) {
        #pragma unroll
        for (int r = 0; r < 4; ++r) {
            const int m = wr * 64 + mi * 16 + rbase + r;
            const size_t rowoff = (size_t)(row0 + m) * F;
            #pragma unroll
            for (int ni = 0; ni < 4; ++ni) {
                const int o = wc * 64 + ni * 16 + lr;
                out[rowoff + o] = acc_t[mi][ni][r] + x[rowoff + o];
            }
        }
    }
}

extern "C" void kernel_launch(void* const* d_in, const int* in_sizes, int n_in,
                              void* d_out, int out_size, void* d_ws, size_t ws_size,
                              hipStream_t stream) {
    const float* x    = (const float*)d_in[0];
    // d_in[1] = h0 : unused by the reference (variant=False path)
    const float* z    = (const float*)d_in[2];
    const float* vals = (const float*)d_in[3];
    const float* W    = (const float*)d_in[4];
    const int* rows   = (const int*)d_in[5];
    const int* cols   = (const int*)d_in[6];
    float* out        = (float*)d_out;
    const int E = in_sizes[3];

    // workspace layout (~50 MB total)
    char* ws = (char*)d_ws;
    short* xb      = (short*)(ws);                               // 32 MB bf16 [NN][F]
    short* WbT     = (short*)(ws + ((size_t)32 << 20));          // 1 MB
    int*   offsets = (int*)  (ws + ((size_t)33 << 20));          // 256 KB + 4
    int*   bcount  = (int*)  (ws + ((size_t)33 << 20) + 264*1024);
    int*   bbase   = (int*)  (ws + ((size_t)33 << 20) + 266*1024);
    int*   bcursor = (int*)  (ws + ((size_t)33 << 20) + 268*1024);
    int2*  tmp     = (int2*) (ws + ((size_t)34 << 20));          // 16 MB
    float* hi      = out;    // gather output lives in d_out; moe_gemm is in-place

    const int nblk = (E + EPB - 1) / EPB;
    hipMemsetAsync(bcount, 0, NB * sizeof(int), stream);
    conv_x<<<(NN * F) / (256 * 8), 256, 0, stream>>>(x, xb);
    prep_w<<<dim3(4, 4, 8), 256, 0, stream>>>(W, WbT);
    bucket_hist<<<nblk, 256, 0, stream>>>(rows, bcount, E);
    bucket_scan<<<1, 256, 0, stream>>>(bcount, bbase, bcursor);
    bucket_scatter<<<nblk, 256, 0, stream>>>(rows, cols, vals, bcursor, tmp, E);
    bucket_to_csr<<<NB, 256, 0, stream>>>(bbase, tmp, offsets);
    gather_rows<<<NN / 4, 256, 0, stream>>>(xb, tmp, offsets, hi);
    moe_gemm<<<NN / BM, 512, 0, stream>>>(hi, z, WbT, x, out);
}

// Round 7
// 1323.093 us; speedup vs baseline: 1.2425x; 1.2425x over previous
//
#include <hip/hip_runtime.h>
#include <hip/hip_bf16.h>

using short8 = __attribute__((ext_vector_type(8))) short;
using f32x4  = __attribute__((ext_vector_type(4))) float;
typedef unsigned int u32;

static constexpr int NN = 65536;   // nodes
static constexpr int F  = 256;     // feat dim
static constexpr int KE = 8;       // experts
static constexpr int KD = KE * F;  // 2048 = GEMM inner dim
static constexpr int NB = 256;     // coarse buckets (row>>8)
static constexpr int EPB = 8192;   // edges per bucket_scatter block
static constexpr int BCAP = 12288; // bucket LDS capacity (avg 8192, +45 sigma margin)

__device__ __forceinline__ short f2bf(float f) {
    union { __hip_bfloat16 h; short s; } u;
    u.h = __float2bfloat16(f);
    return u.s;
}
__device__ __forceinline__ float bf_lo(unsigned u) { return __uint_as_float(u << 16); }
__device__ __forceinline__ float bf_hi(unsigned u) { return __uint_as_float(u & 0xFFFF0000u); }

// async 16B global->LDS (dest = wave-uniform base + lane*16, HW-enforced)
__device__ __forceinline__ void gld_lds16(void* lds, const void* g) {
    __builtin_amdgcn_global_load_lds((const __attribute__((address_space(1))) u32*)g,
                                     (__attribute__((address_space(3))) u32*)lds, 16, 0, 0);
}

// ---------- x f32 -> xb bf16 (halves gather read traffic)
__global__ __launch_bounds__(256)
void conv_x(const float* __restrict__ x, short* __restrict__ xb) {
    const size_t i = ((size_t)blockIdx.x * 256 + threadIdx.x) * 8;
    const float4 a = *(const float4*)(x + i);
    const float4 b = *(const float4*)(x + i + 4);
    short8 p;
    p[0]=f2bf(a.x); p[1]=f2bf(a.y); p[2]=f2bf(a.z); p[3]=f2bf(a.w);
    p[4]=f2bf(b.x); p[5]=f2bf(b.y); p[6]=f2bf(b.z); p[7]=f2bf(b.w);
    *(short8*)(xb + i) = p;
}

// ---------- W [8][256][256] f32 -> WbT [256][2048] bf16, WbT[o][e*256+i] = W[e][i][o]
__global__ void prep_w(const float* __restrict__ W, short* __restrict__ WbT) {
    __shared__ float tile[64][65];
    const int e  = blockIdx.z;
    const int i0 = blockIdx.x * 64;
    const int o0 = blockIdx.y * 64;
    const int c  = threadIdx.x & 63;
    const int r4 = threadIdx.x >> 6;
    for (int rr = r4; rr < 64; rr += 4)
        tile[rr][c] = W[((size_t)e * F + i0 + rr) * F + o0 + c];
    __syncthreads();
    for (int rr = r4; rr < 64; rr += 4)
        WbT[(size_t)(o0 + rr) * KD + e * F + i0 + c] = f2bf(tile[c][rr]);
}

// ---------- P1: coarse-bucket histogram (256 buckets of 256 rows)
__global__ __launch_bounds__(256)
void bucket_hist(const int* __restrict__ rows, int* __restrict__ bcount, int E) {
    __shared__ int h[NB];
    const int tid = threadIdx.x;
    h[tid] = 0;
    __syncthreads();
    const int base = blockIdx.x * EPB;
    const int lim  = min(EPB, E - base);
    for (int i = tid; i < lim; i += 256)
        atomicAdd(&h[rows[base + i] >> 8], 1);
    __syncthreads();
    if (h[tid]) atomicAdd(&bcount[tid], h[tid]);
}

// ---------- P2: 256-wide exclusive scan -> bucket bases + cursors
__global__ __launch_bounds__(256)
void bucket_scan(const int* __restrict__ bcount, int* __restrict__ bbase,
                 int* __restrict__ bcursor) {
    __shared__ int s[NB];
    const int tid = threadIdx.x;
    const int c = bcount[tid];
    s[tid] = c;
    __syncthreads();
    for (int off = 1; off < NB; off <<= 1) {
        int v = (tid >= off) ? s[tid - off] : 0;
        __syncthreads();
        s[tid] += v;
        __syncthreads();
    }
    const int excl = s[tid] - c;
    bbase[tid]   = excl;
    bcursor[tid] = excl;
    if (tid == NB - 1) bbase[NB] = s[tid];
}

// ---------- P3: scatter edges into coarse buckets (L2-merged contiguous runs)
__global__ __launch_bounds__(256)
void bucket_scatter(const int* __restrict__ rows, const int* __restrict__ cols,
                    const float* __restrict__ vals, int* __restrict__ bcursor,
                    int2* __restrict__ tmp, int E) {
    __shared__ int h[NB], wb[NB];
    const int tid = threadIdx.x;
    h[tid] = 0;
    __syncthreads();
    const int base = blockIdx.x * EPB;
    const int lim  = min(EPB, E - base);
    for (int i = tid; i < lim; i += 256)
        atomicAdd(&h[rows[base + i] >> 8], 1);
    __syncthreads();
    const int c = h[tid];
    wb[tid] = c ? atomicAdd(&bcursor[tid], c) : 0;
    h[tid] = 0;
    __syncthreads();
    for (int i = tid; i < lim; i += 256) {
        const int r  = rows[base + i];
        const int bk = r >> 8;
        const int rank = atomicAdd(&h[bk], 1);
        tmp[wb[bk] + rank] = make_int2(((r & 255) << 16) | cols[base + i],
                                       __float_as_int(vals[base + i]));
    }
}

// ---------- P4: one block per bucket: row-CSR + coarse col-sort (8 col-range
// passes of 4MB-of-xb each) so gather sweeps L2-sized col windows.
__global__ __launch_bounds__(256)
void bucket_to_csr(const int* __restrict__ bbase, int2* __restrict__ tmp,
                   int* __restrict__ offsets) {
    __shared__ int2 buf[BCAP];          // 96 KB
    __shared__ int h[NB], off[NB];
    const int tid = threadIdx.x;
    const int k   = blockIdx.x;
    const int beg = bbase[k];
    const int end = bbase[k + 1];
    const int n   = end - beg;
    h[tid] = 0;
    __syncthreads();
    for (int i = tid; i < n; i += 256) {
        const int2 e = tmp[beg + i];
        if (i < BCAP) buf[i] = e;
        atomicAdd(&h[e.x >> 16], 1);
    }
    __syncthreads();
    const int c = h[tid];
    off[tid] = c;
    __syncthreads();
    for (int o = 1; o < NB; o <<= 1) {
        int v = (tid >= o) ? off[tid - o] : 0;
        __syncthreads();
        off[tid] += v;
        __syncthreads();
    }
    const int excl = off[tid] - c;
    offsets[k * NB + tid] = beg + excl;
    if (k == NB - 1 && tid == NB - 1) offsets[NN] = end;
    h[tid] = excl;                      // reuse as within-bucket cursor
    __syncthreads();
    for (int p = 0; p < 8; ++p) {       // col-range passes: cr = col>>13
        for (int i = tid; i < n; i += 256) {
            const int2 e = (i < BCAP) ? buf[i] : tmp[beg + i];
            if (((e.x >> 13) & 7) == p) {
                const int r = e.x >> 16;
                const int pos = atomicAdd(&h[r], 1);
                tmp[beg + pos] = make_int2(e.x & 0xFFFF, e.y);
            }
        }
        __syncthreads();
    }
}

// ---------- gather: per-row segmented accumulate (bf16 x), hi written f32 into d_out
__global__ __launch_bounds__(256)
void gather_rows(const short* __restrict__ xb, const int2* __restrict__ scv,
                 const int* __restrict__ offsets, float* __restrict__ hi) {
    const int lane = threadIdx.x & 63;
    int row = (blockIdx.x << 2) + (threadIdx.x >> 6);
    row = __builtin_amdgcn_readfirstlane(row);
    const int beg = offsets[row];
    const int end = offsets[row + 1];
    float4 acc = {0.f, 0.f, 0.f, 0.f};
    int j = beg;
    for (; j + 8 <= end; j += 8) {
        int2 cc[8], rr[8];
        #pragma unroll
        for (int q = 0; q < 8; ++q) cc[q] = scv[j + q];
        #pragma unroll
        for (int q = 0; q < 8; ++q)
            rr[q] = ((const int2*)(xb + (size_t)cc[q].x * F))[lane];
        #pragma unroll
        for (int q = 0; q < 8; ++q) {
            const float v = __int_as_float(cc[q].y);
            acc.x += v * bf_lo(rr[q].x); acc.y += v * bf_hi(rr[q].x);
            acc.z += v * bf_lo(rr[q].y); acc.w += v * bf_hi(rr[q].y);
        }
    }
    for (; j + 4 <= end; j += 4) {
        int2 cc[4], rr[4];
        #pragma unroll
        for (int q = 0; q < 4; ++q) cc[q] = scv[j + q];
        #pragma unroll
        for (int q = 0; q < 4; ++q)
            rr[q] = ((const int2*)(xb + (size_t)cc[q].x * F))[lane];
        #pragma unroll
        for (int q = 0; q < 4; ++q) {
            const float v = __int_as_float(cc[q].y);
            acc.x += v * bf_lo(rr[q].x); acc.y += v * bf_hi(rr[q].x);
            acc.z += v * bf_lo(rr[q].y); acc.w += v * bf_hi(rr[q].y);
        }
    }
    for (; j < end; ++j) {
        const int2 c0 = scv[j];
        const int2 r0 = ((const int2*)(xb + (size_t)c0.x * F))[lane];
        const float v0 = __int_as_float(c0.y);
        acc.x += v0*bf_lo(r0.x); acc.y += v0*bf_hi(r0.x);
        acc.z += v0*bf_lo(r0.y); acc.w += v0*bf_hi(r0.y);
    }
    ((float4*)(hi + (size_t)row * F))[lane] = acc;
}

// ---------- GEMM: out[n,o] = sum_e z[n,e] * (hi[n,:] @ W[e]) + x[n,o]
// A resident in LDS, read ONCE per i0-block into regs and reused across the 8
// experts (i0-outer / expert-inner; z folded per (i0b,e) — valid by linearity).
// z transposed in LDS so each fold's 4 row-values are one ds_read_b128.
// __launch_bounds__(512,2): VGPR cap 256 (need ~224) — round-6's cap of 128
// spilled acc_e every iteration (2.5 GB scratch writes).
#define BM 128
__global__ __launch_bounds__(512, 2)
void moe_gemm(const float* __restrict__ hi, const float* __restrict__ z,
              const short* __restrict__ WbT, const float* __restrict__ x,
              float* __restrict__ out) {
    __shared__ short A_lds[BM * F];          // 64 KB, XOR-swizzled
    __shared__ short B_lds[2][256 * 64];     // 2 x 32 KB
    __shared__ float z_t[KE][BM];            // 4 KB, transposed
    const int tid  = threadIdx.x;
    const int lane = tid & 63;
    const int w    = tid >> 6;
    const int wr   = w >> 2;
    const int wc   = w & 3;
    const int row0 = blockIdx.x * BM;

    // step s <-> (i0b = s>>3, e = s&7); chunk bytes: e*512 + i0b*128 within WbT row
    auto stageB = [&](int s, int buf) {
        const int kb0 = (s & 7) * 512 + (s >> 3) * 128;
        #pragma unroll
        for (int q = 0; q < 4; ++q) {
            const int d     = (tid + q * 512) * 16;
            const int o     = d >> 7;
            const int kbyte = d & 127;
            const char* src = (const char*)WbT + (size_t)o * (KD * 2) + kb0
                              + (kbyte ^ ((o & 7) << 4));
            gld_lds16((char*)&B_lds[buf][0] + (w * 64 + q * 512) * 16, src);
        }
    };

    for (int idx = tid; idx < BM * KE; idx += 512)
        z_t[idx & 7][idx >> 3] = z[(size_t)row0 * KE + idx];
    stageB(0, 0);
    {
        const int m0 = tid >> 5;
        const int c8 = tid & 31;
        for (int p = 0; p < BM / 16; ++p) {
            const int m = p * 16 + m0;
            const float4* src = (const float4*)(hi + (size_t)(row0 + m) * F + c8 * 8);
            const float4 a = src[0], b = src[1];
            short8 pk;
            pk[0]=f2bf(a.x); pk[1]=f2bf(a.y); pk[2]=f2bf(a.z); pk[3]=f2bf(a.w);
            pk[4]=f2bf(b.x); pk[5]=f2bf(b.y); pk[6]=f2bf(b.z); pk[7]=f2bf(b.w);
            const int idx = (m * F + c8 * 8) ^ ((m & 7) << 3);
            *(short8*)&A_lds[idx] = pk;
        }
    }
    __syncthreads();

    f32x4 acc_t[4][4];
    #pragma unroll
    for (int mi = 0; mi < 4; ++mi)
        #pragma unroll
        for (int ni = 0; ni < 4; ++ni)
            acc_t[mi][ni] = (f32x4){0.f, 0.f, 0.f, 0.f};

    const int lr    = lane & 15;
    const int krow  = 8 * (lane >> 4);
    const int rbase = (lane >> 4) * 4;

    for (int i0b = 0; i0b < 4; ++i0b) {
        const int i0 = i0b * 64;
        short8 af[4][2];                     // A fragments: read once, reuse 8 experts
        #pragma unroll
        for (int ks = 0; ks < 2; ++ks)
            #pragma unroll
            for (int mi = 0; mi < 4; ++mi) {
                const int m = wr * 64 + mi * 16 + lr;
                af[mi][ks] = *(const short8*)&A_lds[(m * F + i0 + ks * 32 + krow) ^ ((m & 7) << 3)];
            }
        for (int e = 0; e < KE; ++e) {
            const int s   = i0b * 8 + e;
            const int cur = s & 1;
            if (s + 1 < 32) stageB(s + 1, cur ^ 1);

            short8 bf[4][2];
            #pragma unroll
            for (int ks = 0; ks < 2; ++ks)
                #pragma unroll
                for (int ni = 0; ni < 4; ++ni) {
                    const int o = wc * 64 + ni * 16 + lr;
                    bf[ni][ks] = *(const short8*)&B_lds[cur][(o * 64 + ks * 32 + krow) ^ ((o & 7) << 3)];
                }
            f32x4 zv[4];
            #pragma unroll
            for (int mi = 0; mi < 4; ++mi)
                zv[mi] = *(const f32x4*)&z_t[e][wr * 64 + mi * 16 + rbase];

            f32x4 acc_e[4][4];
            #pragma unroll
            for (int mi = 0; mi < 4; ++mi)
                #pragma unroll
                for (int ni = 0; ni < 4; ++ni)
                    acc_e[mi][ni] = (f32x4){0.f, 0.f, 0.f, 0.f};
            #pragma unroll
            for (int ks = 0; ks < 2; ++ks)
                #pragma unroll
                for (int mi = 0; mi < 4; ++mi)
                    #pragma unroll
                    for (int ni = 0; ni < 4; ++ni)
                        acc_e[mi][ni] = __builtin_amdgcn_mfma_f32_16x16x32_bf16(
                            af[mi][ks], bf[ni][ks], acc_e[mi][ni], 0, 0, 0);
            #pragma unroll
            for (int mi = 0; mi < 4; ++mi)
                #pragma unroll
                for (int ni = 0; ni < 4; ++ni)
                    #pragma unroll
                    for (int r = 0; r < 4; ++r)
                        acc_t[mi][ni][r] += zv[mi][r] * acc_e[mi][ni][r];
            __syncthreads();
        }
    }

    #pragma unroll
    for (int mi = 0; mi < 4; ++mi) {
        #pragma unroll
        for (int r = 0; r < 4; ++r) {
            const int m = wr * 64 + mi * 16 + rbase + r;
            const size_t rowoff = (size_t)(row0 + m) * F;
            #pragma unroll
            for (int ni = 0; ni < 4; ++ni) {
                const int o = wc * 64 + ni * 16 + lr;
                out[rowoff + o] = acc_t[mi][ni][r] + x[rowoff + o];
            }
        }
    }
}

extern "C" void kernel_launch(void* const* d_in, const int* in_sizes, int n_in,
                              void* d_out, int out_size, void* d_ws, size_t ws_size,
                              hipStream_t stream) {
    const float* x    = (const float*)d_in[0];
    // d_in[1] = h0 : unused by the reference (variant=False path)
    const float* z    = (const float*)d_in[2];
    const float* vals = (const float*)d_in[3];
    const float* W    = (const float*)d_in[4];
    const int* rows   = (const int*)d_in[5];
    const int* cols   = (const int*)d_in[6];
    float* out        = (float*)d_out;
    const int E = in_sizes[3];

    // workspace layout (~50 MB total)
    char* ws = (char*)d_ws;
    short* xb      = (short*)(ws);                               // 32 MB bf16 [NN][F]
    short* WbT     = (short*)(ws + ((size_t)32 << 20));          // 1 MB
    int*   offsets = (int*)  (ws + ((size_t)33 << 20));          // 256 KB + 4
    int*   bcount  = (int*)  (ws + ((size_t)33 << 20) + 264*1024);
    int*   bbase   = (int*)  (ws + ((size_t)33 << 20) + 266*1024);
    int*   bcursor = (int*)  (ws + ((size_t)33 << 20) + 268*1024);
    int2*  tmp     = (int2*) (ws + ((size_t)34 << 20));          // 16 MB
    float* hi      = out;    // gather output lives in d_out; moe_gemm is in-place

    const int nblk = (E + EPB - 1) / EPB;
    hipMemsetAsync(bcount, 0, NB * sizeof(int), stream);
    conv_x<<<(NN * F) / (256 * 8), 256, 0, stream>>>(x, xb);
    prep_w<<<dim3(4, 4, 8), 256, 0, stream>>>(W, WbT);
    bucket_hist<<<nblk, 256, 0, stream>>>(rows, bcount, E);
    bucket_scan<<<1, 256, 0, stream>>>(bcount, bbase, bcursor);
    bucket_scatter<<<nblk, 256, 0, stream>>>(rows, cols, vals, bcursor, tmp, E);
    bucket_to_csr<<<NB, 256, 0, stream>>>(bbase, tmp, offsets);
    gather_rows<<<NN / 4, 256, 0, stream>>>(xb, tmp, offsets, hi);
    moe_gemm<<<NN / BM, 512, 0, stream>>>(hi, z, WbT, x, out);
}

// Round 8
// 384.363 us; speedup vs baseline: 4.2770x; 3.4423x over previous
//
#include <hip/hip_runtime.h>
#include <hip/hip_bf16.h>

using short8 = __attribute__((ext_vector_type(8))) short;
using f32x4  = __attribute__((ext_vector_type(4))) float;
typedef unsigned int u32;

static constexpr int NN = 65536;   // nodes
static constexpr int F  = 256;     // feat dim
static constexpr int KE = 8;       // experts
static constexpr int KD = KE * F;  // 2048 = GEMM inner dim
static constexpr int NB = 256;     // coarse buckets (row>>8)
static constexpr int EPB = 8192;   // edges per bucket_scatter block
static constexpr int BCAP = 12288; // bucket LDS capacity (avg 8192, +45 sigma margin)

__device__ __forceinline__ short f2bf(float f) {
    union { __hip_bfloat16 h; short s; } u;
    u.h = __float2bfloat16(f);
    return u.s;
}
__device__ __forceinline__ float bf_lo(unsigned u) { return __uint_as_float(u << 16); }
__device__ __forceinline__ float bf_hi(unsigned u) { return __uint_as_float(u & 0xFFFF0000u); }

// async 16B global->LDS (dest = wave-uniform base + lane*16, HW-enforced)
__device__ __forceinline__ void gld_lds16(void* lds, const void* g) {
    __builtin_amdgcn_global_load_lds((const __attribute__((address_space(1))) u32*)g,
                                     (__attribute__((address_space(3))) u32*)lds, 16, 0, 0);
}

// ---------- x f32 -> xb bf16 (halves gather read traffic)
__global__ __launch_bounds__(256)
void conv_x(const float* __restrict__ x, short* __restrict__ xb) {
    const size_t i = ((size_t)blockIdx.x * 256 + threadIdx.x) * 8;
    const float4 a = *(const float4*)(x + i);
    const float4 b = *(const float4*)(x + i + 4);
    short8 p;
    p[0]=f2bf(a.x); p[1]=f2bf(a.y); p[2]=f2bf(a.z); p[3]=f2bf(a.w);
    p[4]=f2bf(b.x); p[5]=f2bf(b.y); p[6]=f2bf(b.z); p[7]=f2bf(b.w);
    *(short8*)(xb + i) = p;
}

// ---------- W [8][256][256] f32 -> WbT [256][2048] bf16, WbT[o][e*256+i] = W[e][i][o]
__global__ void prep_w(const float* __restrict__ W, short* __restrict__ WbT) {
    __shared__ float tile[64][65];
    const int e  = blockIdx.z;
    const int i0 = blockIdx.x * 64;
    const int o0 = blockIdx.y * 64;
    const int c  = threadIdx.x & 63;
    const int r4 = threadIdx.x >> 6;
    for (int rr = r4; rr < 64; rr += 4)
        tile[rr][c] = W[((size_t)e * F + i0 + rr) * F + o0 + c];
    __syncthreads();
    for (int rr = r4; rr < 64; rr += 4)
        WbT[(size_t)(o0 + rr) * KD + e * F + i0 + c] = f2bf(tile[c][rr]);
}

// ---------- P1: coarse-bucket histogram (256 buckets of 256 rows)
__global__ __launch_bounds__(256)
void bucket_hist(const int* __restrict__ rows, int* __restrict__ bcount, int E) {
    __shared__ int h[NB];
    const int tid = threadIdx.x;
    h[tid] = 0;
    __syncthreads();
    const int base = blockIdx.x * EPB;
    const int lim  = min(EPB, E - base);
    for (int i = tid; i < lim; i += 256)
        atomicAdd(&h[rows[base + i] >> 8], 1);
    __syncthreads();
    if (h[tid]) atomicAdd(&bcount[tid], h[tid]);
}

// ---------- P2: 256-wide exclusive scan -> bucket bases + cursors
__global__ __launch_bounds__(256)
void bucket_scan(const int* __restrict__ bcount, int* __restrict__ bbase,
                 int* __restrict__ bcursor) {
    __shared__ int s[NB];
    const int tid = threadIdx.x;
    const int c = bcount[tid];
    s[tid] = c;
    __syncthreads();
    for (int off = 1; off < NB; off <<= 1) {
        int v = (tid >= off) ? s[tid - off] : 0;
        __syncthreads();
        s[tid] += v;
        __syncthreads();
    }
    const int excl = s[tid] - c;
    bbase[tid]   = excl;
    bcursor[tid] = excl;
    if (tid == NB - 1) bbase[NB] = s[tid];
}

// ---------- P3: scatter edges into coarse buckets (L2-merged contiguous runs)
__global__ __launch_bounds__(256)
void bucket_scatter(const int* __restrict__ rows, const int* __restrict__ cols,
                    const float* __restrict__ vals, int* __restrict__ bcursor,
                    int2* __restrict__ tmp, int E) {
    __shared__ int h[NB], wb[NB];
    const int tid = threadIdx.x;
    h[tid] = 0;
    __syncthreads();
    const int base = blockIdx.x * EPB;
    const int lim  = min(EPB, E - base);
    for (int i = tid; i < lim; i += 256)
        atomicAdd(&h[rows[base + i] >> 8], 1);
    __syncthreads();
    const int c = h[tid];
    wb[tid] = c ? atomicAdd(&bcursor[tid], c) : 0;
    h[tid] = 0;
    __syncthreads();
    for (int i = tid; i < lim; i += 256) {
        const int r  = rows[base + i];
        const int bk = r >> 8;
        const int rank = atomicAdd(&h[bk], 1);
        tmp[wb[bk] + rank] = make_int2(((r & 255) << 16) | cols[base + i],
                                       __float_as_int(vals[base + i]));
    }
}

// ---------- P4: one block per bucket: row-CSR + coarse col-sort (8 col-range
// passes of 4MB-of-xb each) so gather sweeps L2-sized col windows.
__global__ __launch_bounds__(256)
void bucket_to_csr(const int* __restrict__ bbase, int2* __restrict__ tmp,
                   int* __restrict__ offsets) {
    __shared__ int2 buf[BCAP];          // 96 KB
    __shared__ int h[NB], off[NB];
    const int tid = threadIdx.x;
    const int k   = blockIdx.x;
    const int beg = bbase[k];
    const int end = bbase[k + 1];
    const int n   = end - beg;
    h[tid] = 0;
    __syncthreads();
    for (int i = tid; i < n; i += 256) {
        const int2 e = tmp[beg + i];
        if (i < BCAP) buf[i] = e;
        atomicAdd(&h[e.x >> 16], 1);
    }
    __syncthreads();
    const int c = h[tid];
    off[tid] = c;
    __syncthreads();
    for (int o = 1; o < NB; o <<= 1) {
        int v = (tid >= o) ? off[tid - o] : 0;
        __syncthreads();
        off[tid] += v;
        __syncthreads();
    }
    const int excl = off[tid] - c;
    offsets[k * NB + tid] = beg + excl;
    if (k == NB - 1 && tid == NB - 1) offsets[NN] = end;
    h[tid] = excl;                      // reuse as within-bucket cursor
    __syncthreads();
    for (int p = 0; p < 8; ++p) {       // col-range passes: cr = col>>13
        for (int i = tid; i < n; i += 256) {
            const int2 e = (i < BCAP) ? buf[i] : tmp[beg + i];
            if (((e.x >> 13) & 7) == p) {
                const int r = e.x >> 16;
                const int pos = atomicAdd(&h[r], 1);
                tmp[beg + pos] = make_int2(e.x & 0xFFFF, e.y);
            }
        }
        __syncthreads();
    }
}

// ---------- gather: per-row segmented accumulate (bf16 x), hi written f32 into d_out
__global__ __launch_bounds__(256)
void gather_rows(const short* __restrict__ xb, const int2* __restrict__ scv,
                 const int* __restrict__ offsets, float* __restrict__ hi) {
    const int lane = threadIdx.x & 63;
    int row = (blockIdx.x << 2) + (threadIdx.x >> 6);
    row = __builtin_amdgcn_readfirstlane(row);
    const int beg = offsets[row];
    const int end = offsets[row + 1];
    float4 acc = {0.f, 0.f, 0.f, 0.f};
    int j = beg;
    for (; j + 8 <= end; j += 8) {
        int2 cc[8], rr[8];
        #pragma unroll
        for (int q = 0; q < 8; ++q) cc[q] = scv[j + q];
        #pragma unroll
        for (int q = 0; q < 8; ++q)
            rr[q] = ((const int2*)(xb + (size_t)cc[q].x * F))[lane];
        #pragma unroll
        for (int q = 0; q < 8; ++q) {
            const float v = __int_as_float(cc[q].y);
            acc.x += v * bf_lo(rr[q].x); acc.y += v * bf_hi(rr[q].x);
            acc.z += v * bf_lo(rr[q].y); acc.w += v * bf_hi(rr[q].y);
        }
    }
    for (; j + 4 <= end; j += 4) {
        int2 cc[4], rr[4];
        #pragma unroll
        for (int q = 0; q < 4; ++q) cc[q] = scv[j + q];
        #pragma unroll
        for (int q = 0; q < 4; ++q)
            rr[q] = ((const int2*)(xb + (size_t)cc[q].x * F))[lane];
        #pragma unroll
        for (int q = 0; q < 4; ++q) {
            const float v = __int_as_float(cc[q].y);
            acc.x += v * bf_lo(rr[q].x); acc.y += v * bf_hi(rr[q].x);
            acc.z += v * bf_lo(rr[q].y); acc.w += v * bf_hi(rr[q].y);
        }
    }
    for (; j < end; ++j) {
        const int2 c0 = scv[j];
        const int2 r0 = ((const int2*)(xb + (size_t)c0.x * F))[lane];
        const float v0 = __int_as_float(c0.y);
        acc.x += v0*bf_lo(r0.x); acc.y += v0*bf_hi(r0.x);
        acc.z += v0*bf_lo(r0.y); acc.w += v0*bf_hi(r0.y);
    }
    ((float4*)(hi + (size_t)row * F))[lane] = acc;
}

// ---------- GEMM: out[n,o] = sum_e z[n,e] * (hi[n,:] @ W[e]) + x[n,o]
// REVERTED to the proven round-4 structure (expert-outer, per-step af/bf
// reads, acc_e folded at expert boundaries) — the A-reuse variant needed
// ~280 live regs and spilled (2.2-2.5 GB scratch, MfmaUtil 2%). Kept from
// round 7: z transposed in LDS (fold reads are one ds_read_b128).
#define BM 128
__global__ __launch_bounds__(512, 1)
void moe_gemm(const float* __restrict__ hi, const float* __restrict__ z,
              const short* __restrict__ WbT, const float* __restrict__ x,
              float* __restrict__ out) {
    __shared__ short A_lds[BM * F];          // 64 KB, XOR-swizzled
    __shared__ short B_lds[2][256 * 64];     // 2 x 32 KB
    __shared__ float z_t[KE][BM];            // 4 KB, transposed
    const int tid  = threadIdx.x;
    const int lane = tid & 63;
    const int w    = tid >> 6;
    const int wr   = w >> 2;
    const int wc   = w & 3;
    const int row0 = blockIdx.x * BM;

    // step s <-> (e = s>>2, i0 = (s&3)*64); chunk byte base = s*128 within WbT row
    auto stageB = [&](int s, int buf) {
        const int kb0 = s * 128;
        #pragma unroll
        for (int q = 0; q < 4; ++q) {
            const int d     = (tid + q * 512) * 16;
            const int o     = d >> 7;
            const int kbyte = d & 127;
            const char* src = (const char*)WbT + (size_t)o * (KD * 2) + kb0
                              + (kbyte ^ ((o & 7) << 4));
            gld_lds16((char*)&B_lds[buf][0] + (w * 64 + q * 512) * 16, src);
        }
    };

    for (int idx = tid; idx < BM * KE; idx += 512)
        z_t[idx & 7][idx >> 3] = z[(size_t)row0 * KE + idx];
    stageB(0, 0);
    {
        const int m0 = tid >> 5;
        const int c8 = tid & 31;
        for (int p = 0; p < BM / 16; ++p) {
            const int m = p * 16 + m0;
            const float4* src = (const float4*)(hi + (size_t)(row0 + m) * F + c8 * 8);
            const float4 a = src[0], b = src[1];
            short8 pk;
            pk[0]=f2bf(a.x); pk[1]=f2bf(a.y); pk[2]=f2bf(a.z); pk[3]=f2bf(a.w);
            pk[4]=f2bf(b.x); pk[5]=f2bf(b.y); pk[6]=f2bf(b.z); pk[7]=f2bf(b.w);
            const int idx = (m * F + c8 * 8) ^ ((m & 7) << 3);
            *(short8*)&A_lds[idx] = pk;
        }
    }
    __syncthreads();

    f32x4 acc_t[4][4], acc_e[4][4];
    #pragma unroll
    for (int mi = 0; mi < 4; ++mi)
        #pragma unroll
        for (int ni = 0; ni < 4; ++ni) {
            acc_t[mi][ni] = (f32x4){0.f, 0.f, 0.f, 0.f};
            acc_e[mi][ni] = (f32x4){0.f, 0.f, 0.f, 0.f};
        }

    const int lr    = lane & 15;
    const int krow  = 8 * (lane >> 4);
    const int rbase = (lane >> 4) * 4;

    for (int s = 0; s < 32; ++s) {
        const int cur = s & 1;
        if (s + 1 < 32) stageB(s + 1, cur ^ 1);

        const int i0 = (s & 3) * 64;
        short8 af[4][2], bf[4][2];
        #pragma unroll
        for (int ks = 0; ks < 2; ++ks) {
            #pragma unroll
            for (int mi = 0; mi < 4; ++mi) {
                const int m = wr * 64 + mi * 16 + lr;
                af[mi][ks] = *(const short8*)&A_lds[(m * F + i0 + ks * 32 + krow) ^ ((m & 7) << 3)];
            }
            #pragma unroll
            for (int ni = 0; ni < 4; ++ni) {
                const int o = wc * 64 + ni * 16 + lr;
                bf[ni][ks] = *(const short8*)&B_lds[cur][(o * 64 + ks * 32 + krow) ^ ((o & 7) << 3)];
            }
        }
        #pragma unroll
        for (int ks = 0; ks < 2; ++ks)
            #pragma unroll
            for (int mi = 0; mi < 4; ++mi)
                #pragma unroll
                for (int ni = 0; ni < 4; ++ni)
                    acc_e[mi][ni] = __builtin_amdgcn_mfma_f32_16x16x32_bf16(
                        af[mi][ks], bf[ni][ks], acc_e[mi][ni], 0, 0, 0);

        if ((s & 3) == 3) {            // expert boundary: fold z, reset acc_e
            const int e = s >> 2;
            f32x4 zv[4];
            #pragma unroll
            for (int mi = 0; mi < 4; ++mi)
                zv[mi] = *(const f32x4*)&z_t[e][wr * 64 + mi * 16 + rbase];
            #pragma unroll
            for (int mi = 0; mi < 4; ++mi)
                #pragma unroll
                for (int ni = 0; ni < 4; ++ni)
                    #pragma unroll
                    for (int r = 0; r < 4; ++r) {
                        acc_t[mi][ni][r] += zv[mi][r] * acc_e[mi][ni][r];
                        acc_e[mi][ni][r] = 0.f;
                    }
        }
        __syncthreads();               // buf[cur^1] ready, buf[cur] free
    }

    #pragma unroll
    for (int mi = 0; mi < 4; ++mi) {
        #pragma unroll
        for (int r = 0; r < 4; ++r) {
            const int m = wr * 64 + mi * 16 + rbase + r;
            const size_t rowoff = (size_t)(row0 + m) * F;
            #pragma unroll
            for (int ni = 0; ni < 4; ++ni) {
                const int o = wc * 64 + ni * 16 + lr;
                out[rowoff + o] = acc_t[mi][ni][r] + x[rowoff + o];
            }
        }
    }
}

extern "C" void kernel_launch(void* const* d_in, const int* in_sizes, int n_in,
                              void* d_out, int out_size, void* d_ws, size_t ws_size,
                              hipStream_t stream) {
    const float* x    = (const float*)d_in[0];
    // d_in[1] = h0 : unused by the reference (variant=False path)
    const float* z    = (const float*)d_in[2];
    const float* vals = (const float*)d_in[3];
    const float* W    = (const float*)d_in[4];
    const int* rows   = (const int*)d_in[5];
    const int* cols   = (const int*)d_in[6];
    float* out        = (float*)d_out;
    const int E = in_sizes[3];

    // workspace layout (~50 MB total)
    char* ws = (char*)d_ws;
    short* xb      = (short*)(ws);                               // 32 MB bf16 [NN][F]
    short* WbT     = (short*)(ws + ((size_t)32 << 20));          // 1 MB
    int*   offsets = (int*)  (ws + ((size_t)33 << 20));          // 256 KB + 4
    int*   bcount  = (int*)  (ws + ((size_t)33 << 20) + 264*1024);
    int*   bbase   = (int*)  (ws + ((size_t)33 << 20) + 266*1024);
    int*   bcursor = (int*)  (ws + ((size_t)33 << 20) + 268*1024);
    int2*  tmp     = (int2*) (ws + ((size_t)34 << 20));          // 16 MB
    float* hi      = out;    // gather output lives in d_out; moe_gemm is in-place

    const int nblk = (E + EPB - 1) / EPB;
    hipMemsetAsync(bcount, 0, NB * sizeof(int), stream);
    conv_x<<<(NN * F) / (256 * 8), 256, 0, stream>>>(x, xb);
    prep_w<<<dim3(4, 4, 8), 256, 0, stream>>>(W, WbT);
    bucket_hist<<<nblk, 256, 0, stream>>>(rows, bcount, E);
    bucket_scan<<<1, 256, 0, stream>>>(bcount, bbase, bcursor);
    bucket_scatter<<<nblk, 256, 0, stream>>>(rows, cols, vals, bcursor, tmp, E);
    bucket_to_csr<<<NB, 256, 0, stream>>>(bbase, tmp, offsets);
    gather_rows<<<NN / 4, 256, 0, stream>>>(xb, tmp, offsets, hi);
    moe_gemm<<<NN / BM, 512, 0, stream>>>(hi, z, WbT, x, out);
}

// Round 9
// 357.634 us; speedup vs baseline: 4.5967x; 1.0747x over previous
//
#include <hip/hip_runtime.h>
#include <hip/hip_bf16.h>

using short8 = __attribute__((ext_vector_type(8))) short;
using f32x4  = __attribute__((ext_vector_type(4))) float;
typedef unsigned int u32;

static constexpr int NN = 65536;   // nodes
static constexpr int F  = 256;     // feat dim
static constexpr int KE = 8;       // experts
static constexpr int KD = KE * F;  // 2048 = GEMM inner dim
static constexpr int NB = 256;     // coarse buckets (row>>8)
static constexpr int EPB = 8192;   // edges per bucket_scatter block
static constexpr int BCAP = 12288; // bucket LDS capacity (avg 8192, +45 sigma margin)

__device__ __forceinline__ short f2bf(float f) {
    union { __hip_bfloat16 h; short s; } u;
    u.h = __float2bfloat16(f);
    return u.s;
}
__device__ __forceinline__ float bf_lo(unsigned u) { return __uint_as_float(u << 16); }
__device__ __forceinline__ float bf_hi(unsigned u) { return __uint_as_float(u & 0xFFFF0000u); }

// async 16B global->LDS (dest = wave-uniform base + lane*16, HW-enforced)
__device__ __forceinline__ void gld_lds16(void* lds, const void* g) {
    __builtin_amdgcn_global_load_lds((const __attribute__((address_space(1))) u32*)g,
                                     (__attribute__((address_space(3))) u32*)lds, 16, 0, 0);
}

// ---------- x f32 -> xb bf16 (halves gather read traffic)
__global__ __launch_bounds__(256)
void conv_x(const float* __restrict__ x, short* __restrict__ xb) {
    const size_t i = ((size_t)blockIdx.x * 256 + threadIdx.x) * 8;
    const float4 a = *(const float4*)(x + i);
    const float4 b = *(const float4*)(x + i + 4);
    short8 p;
    p[0]=f2bf(a.x); p[1]=f2bf(a.y); p[2]=f2bf(a.z); p[3]=f2bf(a.w);
    p[4]=f2bf(b.x); p[5]=f2bf(b.y); p[6]=f2bf(b.z); p[7]=f2bf(b.w);
    *(short8*)(xb + i) = p;
}

// ---------- W [8][256][256] f32 -> WbT [256][2048] bf16, WbT[o][e*256+i] = W[e][i][o]
__global__ void prep_w(const float* __restrict__ W, short* __restrict__ WbT) {
    __shared__ float tile[64][65];
    const int e  = blockIdx.z;
    const int i0 = blockIdx.x * 64;
    const int o0 = blockIdx.y * 64;
    const int c  = threadIdx.x & 63;
    const int r4 = threadIdx.x >> 6;
    for (int rr = r4; rr < 64; rr += 4)
        tile[rr][c] = W[((size_t)e * F + i0 + rr) * F + o0 + c];
    __syncthreads();
    for (int rr = r4; rr < 64; rr += 4)
        WbT[(size_t)(o0 + rr) * KD + e * F + i0 + c] = f2bf(tile[c][rr]);
}

// ---------- P1: coarse-bucket histogram (256 buckets of 256 rows)
__global__ __launch_bounds__(256)
void bucket_hist(const int* __restrict__ rows, int* __restrict__ bcount, int E) {
    __shared__ int h[NB];
    const int tid = threadIdx.x;
    h[tid] = 0;
    __syncthreads();
    const int base = blockIdx.x * EPB;
    const int lim  = min(EPB, E - base);
    for (int i = tid; i < lim; i += 256)
        atomicAdd(&h[rows[base + i] >> 8], 1);
    __syncthreads();
    if (h[tid]) atomicAdd(&bcount[tid], h[tid]);
}

// ---------- P2: 256-wide exclusive scan -> bucket bases + cursors
__global__ __launch_bounds__(256)
void bucket_scan(const int* __restrict__ bcount, int* __restrict__ bbase,
                 int* __restrict__ bcursor) {
    __shared__ int s[NB];
    const int tid = threadIdx.x;
    const int c = bcount[tid];
    s[tid] = c;
    __syncthreads();
    for (int off = 1; off < NB; off <<= 1) {
        int v = (tid >= off) ? s[tid - off] : 0;
        __syncthreads();
        s[tid] += v;
        __syncthreads();
    }
    const int excl = s[tid] - c;
    bbase[tid]   = excl;
    bcursor[tid] = excl;
    if (tid == NB - 1) bbase[NB] = s[tid];
}

// ---------- P3: scatter edges into coarse buckets (L2-merged contiguous runs)
__global__ __launch_bounds__(256)
void bucket_scatter(const int* __restrict__ rows, const int* __restrict__ cols,
                    const float* __restrict__ vals, int* __restrict__ bcursor,
                    int2* __restrict__ tmp, int E) {
    __shared__ int h[NB], wb[NB];
    const int tid = threadIdx.x;
    h[tid] = 0;
    __syncthreads();
    const int base = blockIdx.x * EPB;
    const int lim  = min(EPB, E - base);
    for (int i = tid; i < lim; i += 256)
        atomicAdd(&h[rows[base + i] >> 8], 1);
    __syncthreads();
    const int c = h[tid];
    wb[tid] = c ? atomicAdd(&bcursor[tid], c) : 0;
    h[tid] = 0;
    __syncthreads();
    for (int i = tid; i < lim; i += 256) {
        const int r  = rows[base + i];
        const int bk = r >> 8;
        const int rank = atomicAdd(&h[bk], 1);
        tmp[wb[bk] + rank] = make_int2(((r & 255) << 16) | cols[base + i],
                                       __float_as_int(vals[base + i]));
    }
}

// ---------- P4: one block per bucket: exact-row sort (in place) + row offsets.
// (col-sort passes removed: round-8 counters showed FETCH_SIZE unchanged -> null)
__global__ __launch_bounds__(256)
void bucket_to_csr(const int* __restrict__ bbase, int2* __restrict__ tmp,
                   int* __restrict__ offsets) {
    __shared__ int2 buf[BCAP];          // 96 KB
    __shared__ int h[NB], off[NB];
    const int tid = threadIdx.x;
    const int k   = blockIdx.x;
    const int beg = bbase[k];
    const int end = bbase[k + 1];
    const int n   = end - beg;
    h[tid] = 0;
    __syncthreads();
    for (int i = tid; i < n; i += 256) {
        const int2 e = tmp[beg + i];
        if (i < BCAP) buf[i] = e;
        atomicAdd(&h[e.x >> 16], 1);
    }
    __syncthreads();
    const int c = h[tid];
    off[tid] = c;
    __syncthreads();
    for (int o = 1; o < NB; o <<= 1) {
        int v = (tid >= o) ? off[tid - o] : 0;
        __syncthreads();
        off[tid] += v;
        __syncthreads();
    }
    const int excl = off[tid] - c;
    offsets[k * NB + tid] = beg + excl;
    if (k == NB - 1 && tid == NB - 1) offsets[NN] = end;
    h[tid] = excl;                      // reuse as within-bucket cursor
    __syncthreads();
    for (int i = tid; i < n; i += 256) {
        const int2 e = (i < BCAP) ? buf[i] : tmp[beg + i];
        const int r = e.x >> 16;
        const int pos = atomicAdd(&h[r], 1);
        tmp[beg + pos] = make_int2(e.x & 0xFFFF, e.y);
    }
}

// ---------- gather: per-row segmented accumulate (bf16 x), hi written f32 into d_out
__global__ __launch_bounds__(256)
void gather_rows(const short* __restrict__ xb, const int2* __restrict__ scv,
                 const int* __restrict__ offsets, float* __restrict__ hi) {
    const int lane = threadIdx.x & 63;
    int row = (blockIdx.x << 2) + (threadIdx.x >> 6);
    row = __builtin_amdgcn_readfirstlane(row);
    const int beg = offsets[row];
    const int end = offsets[row + 1];
    float4 acc = {0.f, 0.f, 0.f, 0.f};
    int j = beg;
    for (; j + 8 <= end; j += 8) {
        int2 cc[8], rr[8];
        #pragma unroll
        for (int q = 0; q < 8; ++q) cc[q] = scv[j + q];
        #pragma unroll
        for (int q = 0; q < 8; ++q)
            rr[q] = ((const int2*)(xb + (size_t)cc[q].x * F))[lane];
        #pragma unroll
        for (int q = 0; q < 8; ++q) {
            const float v = __int_as_float(cc[q].y);
            acc.x += v * bf_lo(rr[q].x); acc.y += v * bf_hi(rr[q].x);
            acc.z += v * bf_lo(rr[q].y); acc.w += v * bf_hi(rr[q].y);
        }
    }
    for (; j + 4 <= end; j += 4) {
        int2 cc[4], rr[4];
        #pragma unroll
        for (int q = 0; q < 4; ++q) cc[q] = scv[j + q];
        #pragma unroll
        for (int q = 0; q < 4; ++q)
            rr[q] = ((const int2*)(xb + (size_t)cc[q].x * F))[lane];
        #pragma unroll
        for (int q = 0; q < 4; ++q) {
            const float v = __int_as_float(cc[q].y);
            acc.x += v * bf_lo(rr[q].x); acc.y += v * bf_hi(rr[q].x);
            acc.z += v * bf_lo(rr[q].y); acc.w += v * bf_hi(rr[q].y);
        }
    }
    for (; j < end; ++j) {
        const int2 c0 = scv[j];
        const int2 r0 = ((const int2*)(xb + (size_t)c0.x * F))[lane];
        const float v0 = __int_as_float(c0.y);
        acc.x += v0*bf_lo(r0.x); acc.y += v0*bf_hi(r0.x);
        acc.z += v0*bf_lo(r0.y); acc.w += v0*bf_hi(r0.y);
    }
    ((float4*)(hi + (size_t)row * F))[lane] = acc;
}

// ---------- GEMM: out[n,o] = sum_e z[n,e] * (hi[n,:] @ W[e]) + x[n,o]
// T3/T4 counted-vmcnt pipeline: BK=32, B triple-buffered via global_load_lds,
// A resident (8 slices of [128][32], 64B rows, ^((m&3)<<4) bank swizzle).
// Steps end with s_waitcnt vmcnt(2) + raw s_barrier — prefetch loads stay in
// flight across the barrier instead of the __syncthreads vmcnt(0) drain.
#define BM 128
__global__ __launch_bounds__(512, 1)
void moe_gemm(const float* __restrict__ hi, const float* __restrict__ z,
              const short* __restrict__ WbT, const float* __restrict__ x,
              float* __restrict__ out) {
    __shared__ short A_lds[8][BM * 32];      // 64 KB: slice i0b, row m, 64B rows
    __shared__ short B_lds[3][256 * 32];     // 3 x 16 KB: row o, 64B rows
    __shared__ float z_t[KE][BM];            // 4 KB, transposed
    const int tid  = threadIdx.x;
    const int lane = tid & 63;
    const int w    = tid >> 6;
    const int wr   = w >> 2;
    const int wc   = w & 3;
    const int row0 = blockIdx.x * BM;

    // stage B chunk s (= expert s>>3, k-slice (s&7)*32) into buf: 2 x 16B/thread.
    // Linear LDS dest; source pre-swizzled by ^((o&3)<<4) within each 64B row.
    auto stageB = [&](int s, int buf) {
        const int kb0 = s * 64;
        #pragma unroll
        for (int q = 0; q < 2; ++q) {
            const int d  = (tid + q * 512) * 16;       // 0..16383
            const int o  = d >> 6;
            const int kb = d & 63;
            const char* src = (const char*)WbT + (size_t)o * (KD * 2) + kb0
                              + (kb ^ ((o & 3) << 4));
            gld_lds16((char*)&B_lds[buf][0] + d, src);
        }
    };

    stageB(0, 0);
    stageB(1, 1);
    for (int idx = tid; idx < BM * KE; idx += 512)
        z_t[idx & 7][idx >> 3] = z[(size_t)row0 * KE + idx];
    {   // stage A: hi f32 -> bf16, slice layout + swizzle
        const int m0 = tid >> 5;
        const int c8 = tid & 31;       // 8-float chunk: slice c8>>2, 16B pos c8&3
        for (int p = 0; p < BM / 16; ++p) {
            const int m = p * 16 + m0;
            const float4* src = (const float4*)(hi + (size_t)(row0 + m) * F + c8 * 8);
            const float4 a = src[0], b = src[1];
            short8 pk;
            pk[0]=f2bf(a.x); pk[1]=f2bf(a.y); pk[2]=f2bf(a.z); pk[3]=f2bf(a.w);
            pk[4]=f2bf(b.x); pk[5]=f2bf(b.y); pk[6]=f2bf(b.z); pk[7]=f2bf(b.w);
            const int byte = m * 64 + (((c8 & 3) * 16) ^ ((m & 3) << 4));
            *(short8*)((char*)&A_lds[c8 >> 2][0] + byte) = pk;
        }
    }
    __syncthreads();   // prologue only: drains stage(0),stage(1) + A/z writes

    f32x4 acc_t[4][4], acc_e[4][4];
    #pragma unroll
    for (int mi = 0; mi < 4; ++mi)
        #pragma unroll
        for (int ni = 0; ni < 4; ++ni) {
            acc_t[mi][ni] = (f32x4){0.f, 0.f, 0.f, 0.f};
            acc_e[mi][ni] = (f32x4){0.f, 0.f, 0.f, 0.f};
        }

    const int lr    = lane & 15;
    const int kb16  = (lane >> 4) * 16;    // 16B k-offset within 64B row
    const int rbase = (lane >> 4) * 4;

    auto step = [&](int s, int cur) {
        short8 af[4], bf[4];
        #pragma unroll
        for (int mi = 0; mi < 4; ++mi) {
            const int m = wr * 64 + mi * 16 + lr;
            af[mi] = *(const short8*)((const char*)&A_lds[s & 7][0]
                        + m * 64 + (kb16 ^ ((m & 3) << 4)));
        }
        #pragma unroll
        for (int ni = 0; ni < 4; ++ni) {
            const int o = wc * 64 + ni * 16 + lr;
            bf[ni] = *(const short8*)((const char*)&B_lds[cur][0]
                        + o * 64 + (kb16 ^ ((o & 3) << 4)));
        }
        #pragma unroll
        for (int mi = 0; mi < 4; ++mi)
            #pragma unroll
            for (int ni = 0; ni < 4; ++ni)
                acc_e[mi][ni] = __builtin_amdgcn_mfma_f32_16x16x32_bf16(
                    af[mi], bf[ni], acc_e[mi][ni], 0, 0, 0);
        if ((s & 7) == 7) {            // expert boundary: fold z, reset acc_e
            const int e = s >> 3;
            f32x4 zv[4];
            #pragma unroll
            for (int mi = 0; mi < 4; ++mi)
                zv[mi] = *(const f32x4*)&z_t[e][wr * 64 + mi * 16 + rbase];
            #pragma unroll
            for (int mi = 0; mi < 4; ++mi)
                #pragma unroll
                for (int ni = 0; ni < 4; ++ni)
                    #pragma unroll
                    for (int r = 0; r < 4; ++r) {
                        acc_t[mi][ni][r] += zv[mi][r] * acc_e[mi][ni][r];
                        acc_e[mi][ni][r] = 0.f;
                    }
        }
    };

    int nxt = 2;                        // buffer index of step s+2 ( (s+2)%3 )
    for (int s = 0; s < 62; ++s) {
        stageB(s + 2, nxt);
        step(s, nxt == 2 ? (s % 3) : (s % 3));  // cur = s%3
        asm volatile("s_waitcnt vmcnt(2)" ::: "memory");
        __builtin_amdgcn_s_barrier();
        __builtin_amdgcn_sched_barrier(0);
        nxt = (nxt == 2) ? 0 : nxt + 1;
    }
    step(62, 62 % 3);
    asm volatile("s_waitcnt vmcnt(0)" ::: "memory");
    __builtin_amdgcn_s_barrier();
    __builtin_amdgcn_sched_barrier(0);
    step(63, 63 % 3);

    #pragma unroll
    for (int mi = 0; mi < 4; ++mi) {
        #pragma unroll
        for (int r = 0; r < 4; ++r) {
            const int m = wr * 64 + mi * 16 + rbase + r;
            const size_t rowoff = (size_t)(row0 + m) * F;
            #pragma unroll
            for (int ni = 0; ni < 4; ++ni) {
                const int o = wc * 64 + ni * 16 + lr;
                out[rowoff + o] = acc_t[mi][ni][r] + x[rowoff + o];
            }
        }
    }
}

extern "C" void kernel_launch(void* const* d_in, const int* in_sizes, int n_in,
                              void* d_out, int out_size, void* d_ws, size_t ws_size,
                              hipStream_t stream) {
    const float* x    = (const float*)d_in[0];
    // d_in[1] = h0 : unused by the reference (variant=False path)
    const float* z    = (const float*)d_in[2];
    const float* vals = (const float*)d_in[3];
    const float* W    = (const float*)d_in[4];
    const int* rows   = (const int*)d_in[5];
    const int* cols   = (const int*)d_in[6];
    float* out        = (float*)d_out;
    const int E = in_sizes[3];

    // workspace layout (~50 MB total)
    char* ws = (char*)d_ws;
    short* xb      = (short*)(ws);                               // 32 MB bf16 [NN][F]
    short* WbT     = (short*)(ws + ((size_t)32 << 20));          // 1 MB
    int*   offsets = (int*)  (ws + ((size_t)33 << 20));          // 256 KB + 4
    int*   bcount  = (int*)  (ws + ((size_t)33 << 20) + 264*1024);
    int*   bbase   = (int*)  (ws + ((size_t)33 << 20) + 266*1024);
    int*   bcursor = (int*)  (ws + ((size_t)33 << 20) + 268*1024);
    int2*  tmp     = (int2*) (ws + ((size_t)34 << 20));          // 16 MB
    float* hi      = out;    // gather output lives in d_out; moe_gemm is in-place

    const int nblk = (E + EPB - 1) / EPB;
    hipMemsetAsync(bcount, 0, NB * sizeof(int), stream);
    conv_x<<<(NN * F) / (256 * 8), 256, 0, stream>>>(x, xb);
    prep_w<<<dim3(4, 4, 8), 256, 0, stream>>>(W, WbT);
    bucket_hist<<<nblk, 256, 0, stream>>>(rows, bcount, E);
    bucket_scan<<<1, 256, 0, stream>>>(bcount, bbase, bcursor);
    bucket_scatter<<<nblk, 256, 0, stream>>>(rows, cols, vals, bcursor, tmp, E);
    bucket_to_csr<<<NB, 256, 0, stream>>>(bbase, tmp, offsets);
    gather_rows<<<NN / 4, 256, 0, stream>>>(xb, tmp, offsets, hi);
    moe_gemm<<<NN / BM, 512, 0, stream>>>(hi, z, WbT, x, out);
}

// Round 10
// 283.025 us; speedup vs baseline: 5.8084x; 1.2636x over previous
//
#include <hip/hip_runtime.h>
#include <hip/hip_bf16.h>

using short8 = __attribute__((ext_vector_type(8))) short;
using f32x4  = __attribute__((ext_vector_type(4))) float;
using f32x2  = __attribute__((ext_vector_type(2))) float;
typedef unsigned int u32;

static constexpr int NN = 65536;   // nodes
static constexpr int F  = 256;     // feat dim
static constexpr int KE = 8;       // experts
static constexpr int KD = KE * F;  // 2048 = GEMM inner dim
static constexpr int NB = 256;     // coarse buckets (row>>8)
static constexpr int EPB = 8192;   // edges per bucket_scatter block
static constexpr int BCAP = 12288; // bucket LDS capacity (avg 8192, +45 sigma margin)

__device__ __forceinline__ short f2bf(float f) {
    union { __hip_bfloat16 h; short s; } u;
    u.h = __float2bfloat16(f);
    return u.s;
}

// async 16B global->LDS (dest = wave-uniform base + lane*16, HW-enforced)
__device__ __forceinline__ void gld_lds16(void* lds, const void* g) {
    __builtin_amdgcn_global_load_lds((const __attribute__((address_space(1))) u32*)g,
                                     (__attribute__((address_space(3))) u32*)lds, 16, 0, 0);
}

// ---------- x f32 -> xq fp8 e4m3 (quarters gather read traffic vs f32)
// x ~ N(0,1): well inside e4m3 range (+-448), RNE via HW cvt_pk.
__global__ __launch_bounds__(256)
void conv_x8(const float* __restrict__ x, u32* __restrict__ xq) {
    const size_t i = ((size_t)blockIdx.x * 256 + threadIdx.x) * 8;
    const float4 a = *(const float4*)(x + i);
    const float4 b = *(const float4*)(x + i + 4);
    u32 w0 = __builtin_amdgcn_cvt_pk_fp8_f32(a.x, a.y, 0, false);
    w0     = __builtin_amdgcn_cvt_pk_fp8_f32(a.z, a.w, w0, true);
    u32 w1 = __builtin_amdgcn_cvt_pk_fp8_f32(b.x, b.y, 0, false);
    w1     = __builtin_amdgcn_cvt_pk_fp8_f32(b.z, b.w, w1, true);
    *(uint2*)(xq + i / 4) = make_uint2(w0, w1);
}

// ---------- W [8][256][256] f32 -> WbT [256][2048] bf16, WbT[o][e*256+i] = W[e][i][o]
__global__ void prep_w(const float* __restrict__ W, short* __restrict__ WbT) {
    __shared__ float tile[64][65];
    const int e  = blockIdx.z;
    const int i0 = blockIdx.x * 64;
    const int o0 = blockIdx.y * 64;
    const int c  = threadIdx.x & 63;
    const int r4 = threadIdx.x >> 6;
    for (int rr = r4; rr < 64; rr += 4)
        tile[rr][c] = W[((size_t)e * F + i0 + rr) * F + o0 + c];
    __syncthreads();
    for (int rr = r4; rr < 64; rr += 4)
        WbT[(size_t)(o0 + rr) * KD + e * F + i0 + c] = f2bf(tile[c][rr]);
}

// ---------- P1: coarse-bucket histogram (256 buckets of 256 rows)
__global__ __launch_bounds__(256)
void bucket_hist(const int* __restrict__ rows, int* __restrict__ bcount, int E) {
    __shared__ int h[NB];
    const int tid = threadIdx.x;
    h[tid] = 0;
    __syncthreads();
    const int base = blockIdx.x * EPB;
    const int lim  = min(EPB, E - base);
    for (int i = tid; i < lim; i += 256)
        atomicAdd(&h[rows[base + i] >> 8], 1);
    __syncthreads();
    if (h[tid]) atomicAdd(&bcount[tid], h[tid]);
}

// ---------- P2: 256-wide exclusive scan -> bucket bases + cursors
__global__ __launch_bounds__(256)
void bucket_scan(const int* __restrict__ bcount, int* __restrict__ bbase,
                 int* __restrict__ bcursor) {
    __shared__ int s[NB];
    const int tid = threadIdx.x;
    const int c = bcount[tid];
    s[tid] = c;
    __syncthreads();
    for (int off = 1; off < NB; off <<= 1) {
        int v = (tid >= off) ? s[tid - off] : 0;
        __syncthreads();
        s[tid] += v;
        __syncthreads();
    }
    const int excl = s[tid] - c;
    bbase[tid]   = excl;
    bcursor[tid] = excl;
    if (tid == NB - 1) bbase[NB] = s[tid];
}

// ---------- P3: scatter edges into coarse buckets (L2-merged contiguous runs)
__global__ __launch_bounds__(256)
void bucket_scatter(const int* __restrict__ rows, const int* __restrict__ cols,
                    const float* __restrict__ vals, int* __restrict__ bcursor,
                    int2* __restrict__ tmp, int E) {
    __shared__ int h[NB], wb[NB];
    const int tid = threadIdx.x;
    h[tid] = 0;
    __syncthreads();
    const int base = blockIdx.x * EPB;
    const int lim  = min(EPB, E - base);
    for (int i = tid; i < lim; i += 256)
        atomicAdd(&h[rows[base + i] >> 8], 1);
    __syncthreads();
    const int c = h[tid];
    wb[tid] = c ? atomicAdd(&bcursor[tid], c) : 0;
    h[tid] = 0;
    __syncthreads();
    for (int i = tid; i < lim; i += 256) {
        const int r  = rows[base + i];
        const int bk = r >> 8;
        const int rank = atomicAdd(&h[bk], 1);
        tmp[wb[bk] + rank] = make_int2(((r & 255) << 16) | cols[base + i],
                                       __float_as_int(vals[base + i]));
    }
}

// ---------- P4: one block per bucket: exact-row sort (in place) + row offsets
__global__ __launch_bounds__(256)
void bucket_to_csr(const int* __restrict__ bbase, int2* __restrict__ tmp,
                   int* __restrict__ offsets) {
    __shared__ int2 buf[BCAP];          // 96 KB
    __shared__ int h[NB], off[NB];
    const int tid = threadIdx.x;
    const int k   = blockIdx.x;
    const int beg = bbase[k];
    const int end = bbase[k + 1];
    const int n   = end - beg;
    h[tid] = 0;
    __syncthreads();
    for (int i = tid; i < n; i += 256) {
        const int2 e = tmp[beg + i];
        if (i < BCAP) buf[i] = e;
        atomicAdd(&h[e.x >> 16], 1);
    }
    __syncthreads();
    const int c = h[tid];
    off[tid] = c;
    __syncthreads();
    for (int o = 1; o < NB; o <<= 1) {
        int v = (tid >= o) ? off[tid - o] : 0;
        __syncthreads();
        off[tid] += v;
        __syncthreads();
    }
    const int excl = off[tid] - c;
    offsets[k * NB + tid] = beg + excl;
    if (k == NB - 1 && tid == NB - 1) offsets[NN] = end;
    h[tid] = excl;                      // reuse as within-bucket cursor
    __syncthreads();
    for (int i = tid; i < n; i += 256) {
        const int2 e = (i < BCAP) ? buf[i] : tmp[beg + i];
        const int r = e.x >> 16;
        const int pos = atomicAdd(&h[r], 1);
        tmp[beg + pos] = make_int2(e.x & 0xFFFF, e.y);
    }
}

// ---------- gather: per-row segmented accumulate (fp8 x), hi written f32 into d_out
// lane reads 4B (4 fp8) per edge; HW cvt_pk_f32_fp8 unpacks 2 at a time.
__global__ __launch_bounds__(256)
void gather_rows(const u32* __restrict__ xq, const int2* __restrict__ scv,
                 const int* __restrict__ offsets, float* __restrict__ hi) {
    const int lane = threadIdx.x & 63;
    int row = (blockIdx.x << 2) + (threadIdx.x >> 6);
    row = __builtin_amdgcn_readfirstlane(row);
    const int beg = offsets[row];
    const int end = offsets[row + 1];
    float4 acc = {0.f, 0.f, 0.f, 0.f};
    int j = beg;
    for (; j + 8 <= end; j += 8) {
        int2 cc[8];
        u32  rr[8];
        #pragma unroll
        for (int q = 0; q < 8; ++q) cc[q] = scv[j + q];
        #pragma unroll
        for (int q = 0; q < 8; ++q)
            rr[q] = (xq + (size_t)cc[q].x * (F / 4))[lane];
        #pragma unroll
        for (int q = 0; q < 8; ++q) {
            const float v = __int_as_float(cc[q].y);
            const f32x2 lo = __builtin_amdgcn_cvt_pk_f32_fp8(rr[q], false);
            const f32x2 hi2 = __builtin_amdgcn_cvt_pk_f32_fp8(rr[q], true);
            acc.x += v * lo[0];  acc.y += v * lo[1];
            acc.z += v * hi2[0]; acc.w += v * hi2[1];
        }
    }
    for (; j < end; ++j) {
        const int2 c0 = scv[j];
        const u32 r0 = (xq + (size_t)c0.x * (F / 4))[lane];
        const float v0 = __int_as_float(c0.y);
        const f32x2 lo = __builtin_amdgcn_cvt_pk_f32_fp8(r0, false);
        const f32x2 hi2 = __builtin_amdgcn_cvt_pk_f32_fp8(r0, true);
        acc.x += v0 * lo[0];  acc.y += v0 * lo[1];
        acc.z += v0 * hi2[0]; acc.w += v0 * hi2[1];
    }
    ((float4*)(hi + (size_t)row * F))[lane] = acc;
}

// ---------- GEMM: out[n,o] = sum_e z[n,e] * (hi[n,:] @ W[e]) + x[n,o]
// T3/T4 counted-vmcnt pipeline: BK=32, B triple-buffered via global_load_lds,
// A resident (8 slices of [128][32], 64B rows, ^((m&3)<<4) bank swizzle).
#define BM 128
__global__ __launch_bounds__(512, 1)
void moe_gemm(const float* __restrict__ hi, const float* __restrict__ z,
              const short* __restrict__ WbT, const float* __restrict__ x,
              float* __restrict__ out) {
    __shared__ short A_lds[8][BM * 32];      // 64 KB: slice i0b, row m, 64B rows
    __shared__ short B_lds[3][256 * 32];     // 3 x 16 KB: row o, 64B rows
    __shared__ float z_t[KE][BM];            // 4 KB, transposed
    const int tid  = threadIdx.x;
    const int lane = tid & 63;
    const int w    = tid >> 6;
    const int wr   = w >> 2;
    const int wc   = w & 3;
    const int row0 = blockIdx.x * BM;

    auto stageB = [&](int s, int buf) {
        const int kb0 = s * 64;
        #pragma unroll
        for (int q = 0; q < 2; ++q) {
            const int d  = (tid + q * 512) * 16;       // 0..16383
            const int o  = d >> 6;
            const int kb = d & 63;
            const char* src = (const char*)WbT + (size_t)o * (KD * 2) + kb0
                              + (kb ^ ((o & 3) << 4));
            gld_lds16((char*)&B_lds[buf][0] + d, src);
        }
    };

    stageB(0, 0);
    stageB(1, 1);
    for (int idx = tid; idx < BM * KE; idx += 512)
        z_t[idx & 7][idx >> 3] = z[(size_t)row0 * KE + idx];
    {   // stage A: hi f32 -> bf16, slice layout + swizzle
        const int m0 = tid >> 5;
        const int c8 = tid & 31;       // 8-float chunk: slice c8>>2, 16B pos c8&3
        for (int p = 0; p < BM / 16; ++p) {
            const int m = p * 16 + m0;
            const float4* src = (const float4*)(hi + (size_t)(row0 + m) * F + c8 * 8);
            const float4 a = src[0], b = src[1];
            short8 pk;
            pk[0]=f2bf(a.x); pk[1]=f2bf(a.y); pk[2]=f2bf(a.z); pk[3]=f2bf(a.w);
            pk[4]=f2bf(b.x); pk[5]=f2bf(b.y); pk[6]=f2bf(b.z); pk[7]=f2bf(b.w);
            const int byte = m * 64 + (((c8 & 3) * 16) ^ ((m & 3) << 4));
            *(short8*)((char*)&A_lds[c8 >> 2][0] + byte) = pk;
        }
    }
    __syncthreads();   // prologue only

    f32x4 acc_t[4][4], acc_e[4][4];
    #pragma unroll
    for (int mi = 0; mi < 4; ++mi)
        #pragma unroll
        for (int ni = 0; ni < 4; ++ni) {
            acc_t[mi][ni] = (f32x4){0.f, 0.f, 0.f, 0.f};
            acc_e[mi][ni] = (f32x4){0.f, 0.f, 0.f, 0.f};
        }

    const int lr    = lane & 15;
    const int kb16  = (lane >> 4) * 16;    // 16B k-offset within 64B row
    const int rbase = (lane >> 4) * 4;

    auto step = [&](int s, int cur) {
        short8 af[4], bf[4];
        #pragma unroll
        for (int mi = 0; mi < 4; ++mi) {
            const int m = wr * 64 + mi * 16 + lr;
            af[mi] = *(const short8*)((const char*)&A_lds[s & 7][0]
                        + m * 64 + (kb16 ^ ((m & 3) << 4)));
        }
        #pragma unroll
        for (int ni = 0; ni < 4; ++ni) {
            const int o = wc * 64 + ni * 16 + lr;
            bf[ni] = *(const short8*)((const char*)&B_lds[cur][0]
                        + o * 64 + (kb16 ^ ((o & 3) << 4)));
        }
        #pragma unroll
        for (int mi = 0; mi < 4; ++mi)
            #pragma unroll
            for (int ni = 0; ni < 4; ++ni)
                acc_e[mi][ni] = __builtin_amdgcn_mfma_f32_16x16x32_bf16(
                    af[mi], bf[ni], acc_e[mi][ni], 0, 0, 0);
        if ((s & 7) == 7) {            // expert boundary: fold z, reset acc_e
            const int e = s >> 3;
            f32x4 zv[4];
            #pragma unroll
            for (int mi = 0; mi < 4; ++mi)
                zv[mi] = *(const f32x4*)&z_t[e][wr * 64 + mi * 16 + rbase];
            #pragma unroll
            for (int mi = 0; mi < 4; ++mi)
                #pragma unroll
                for (int ni = 0; ni < 4; ++ni)
                    #pragma unroll
                    for (int r = 0; r < 4; ++r) {
                        acc_t[mi][ni][r] += zv[mi][r] * acc_e[mi][ni][r];
                        acc_e[mi][ni][r] = 0.f;
                    }
        }
    };

    int nxt = 2;                        // buffer of step s+2 = (s+2)%3
    for (int s = 0; s < 62; ++s) {
        stageB(s + 2, nxt);
        step(s, s % 3);
        asm volatile("s_waitcnt vmcnt(2)" ::: "memory");
        __builtin_amdgcn_s_barrier();
        __builtin_amdgcn_sched_barrier(0);
        nxt = (nxt == 2) ? 0 : nxt + 1;
    }
    step(62, 62 % 3);
    asm volatile("s_waitcnt vmcnt(0)" ::: "memory");
    __builtin_amdgcn_s_barrier();
    __builtin_amdgcn_sched_barrier(0);
    step(63, 63 % 3);

    #pragma unroll
    for (int mi = 0; mi < 4; ++mi) {
        #pragma unroll
        for (int r = 0; r < 4; ++r) {
            const int m = wr * 64 + mi * 16 + rbase + r;
            const size_t rowoff = (size_t)(row0 + m) * F;
            #pragma unroll
            for (int ni = 0; ni < 4; ++ni) {
                const int o = wc * 64 + ni * 16 + lr;
                out[rowoff + o] = acc_t[mi][ni][r] + x[rowoff + o];
            }
        }
    }
}

extern "C" void kernel_launch(void* const* d_in, const int* in_sizes, int n_in,
                              void* d_out, int out_size, void* d_ws, size_t ws_size,
                              hipStream_t stream) {
    const float* x    = (const float*)d_in[0];
    // d_in[1] = h0 : unused by the reference (variant=False path)
    const float* z    = (const float*)d_in[2];
    const float* vals = (const float*)d_in[3];
    const float* W    = (const float*)d_in[4];
    const int* rows   = (const int*)d_in[5];
    const int* cols   = (const int*)d_in[6];
    float* out        = (float*)d_out;
    const int E = in_sizes[3];

    // workspace layout (~34 MB total)
    char* ws = (char*)d_ws;
    u32*   xq      = (u32*)  (ws);                               // 16 MB fp8 [NN][F]
    short* WbT     = (short*)(ws + ((size_t)16 << 20));          // 1 MB
    int*   offsets = (int*)  (ws + ((size_t)17 << 20));          // 256 KB + 4
    int*   bcount  = (int*)  (ws + ((size_t)17 << 20) + 264*1024);
    int*   bbase   = (int*)  (ws + ((size_t)17 << 20) + 266*1024);
    int*   bcursor = (int*)  (ws + ((size_t)17 << 20) + 268*1024);
    int2*  tmp     = (int2*) (ws + ((size_t)18 << 20));          // 16 MB
    float* hi      = out;    // gather output lives in d_out; moe_gemm is in-place

    const int nblk = (E + EPB - 1) / EPB;
    hipMemsetAsync(bcount, 0, NB * sizeof(int), stream);
    conv_x8<<<(NN * F) / (256 * 8), 256, 0, stream>>>(x, xq);
    prep_w<<<dim3(4, 4, 8), 256, 0, stream>>>(W, WbT);
    bucket_hist<<<nblk, 256, 0, stream>>>(rows, bcount, E);
    bucket_scan<<<1, 256, 0, stream>>>(bcount, bbase, bcursor);
    bucket_scatter<<<nblk, 256, 0, stream>>>(rows, cols, vals, bcursor, tmp, E);
    bucket_to_csr<<<NB, 256, 0, stream>>>(bbase, tmp, offsets);
    gather_rows<<<NN / 4, 256, 0, stream>>>(xq, tmp, offsets, hi);
    moe_gemm<<<NN / BM, 512, 0, stream>>>(hi, z, WbT, x, out);
}

// Round 11
// 271.876 us; speedup vs baseline: 6.0466x; 1.0410x over previous
//
#include <hip/hip_runtime.h>
#include <hip/hip_bf16.h>

using short8 = __attribute__((ext_vector_type(8))) short;
using f32x4  = __attribute__((ext_vector_type(4))) float;
using f32x2  = __attribute__((ext_vector_type(2))) float;
typedef unsigned int u32;

static constexpr int NN = 65536;   // nodes
static constexpr int F  = 256;     // feat dim
static constexpr int KE = 8;       // experts
static constexpr int KD = KE * F;  // 2048 = GEMM inner dim
static constexpr int NB = 256;     // coarse buckets (row>>8)
static constexpr int EPB = 8192;   // edges per bucket_scatter block
static constexpr int BCAP = 12288; // bucket LDS capacity (avg 8192, +45 sigma margin)

__device__ __forceinline__ short f2bf(float f) {
    union { __hip_bfloat16 h; short s; } u;
    u.h = __float2bfloat16(f);
    return u.s;
}

// async 16B global->LDS (dest = wave-uniform base + lane*16, HW-enforced)
__device__ __forceinline__ void gld_lds16(void* lds, const void* g) {
    __builtin_amdgcn_global_load_lds((const __attribute__((address_space(1))) u32*)g,
                                     (__attribute__((address_space(3))) u32*)lds, 16, 0, 0);
}

// ---------- x f32 -> xq fp8 e4m3 (quarters gather read traffic vs f32)
__global__ __launch_bounds__(256)
void conv_x8(const float* __restrict__ x, u32* __restrict__ xq) {
    const size_t i = ((size_t)blockIdx.x * 256 + threadIdx.x) * 8;
    const float4 a = *(const float4*)(x + i);
    const float4 b = *(const float4*)(x + i + 4);
    u32 w0 = __builtin_amdgcn_cvt_pk_fp8_f32(a.x, a.y, 0, false);
    w0     = __builtin_amdgcn_cvt_pk_fp8_f32(a.z, a.w, w0, true);
    u32 w1 = __builtin_amdgcn_cvt_pk_fp8_f32(b.x, b.y, 0, false);
    w1     = __builtin_amdgcn_cvt_pk_fp8_f32(b.z, b.w, w1, true);
    *(uint2*)(xq + i / 4) = make_uint2(w0, w1);
}

// ---------- W [8][256][256] f32 -> WbT [256][2048] bf16, WbT[o][e*256+i] = W[e][i][o]
__global__ void prep_w(const float* __restrict__ W, short* __restrict__ WbT) {
    __shared__ float tile[64][65];
    const int e  = blockIdx.z;
    const int i0 = blockIdx.x * 64;
    const int o0 = blockIdx.y * 64;
    const int c  = threadIdx.x & 63;
    const int r4 = threadIdx.x >> 6;
    for (int rr = r4; rr < 64; rr += 4)
        tile[rr][c] = W[((size_t)e * F + i0 + rr) * F + o0 + c];
    __syncthreads();
    for (int rr = r4; rr < 64; rr += 4)
        WbT[(size_t)(o0 + rr) * KD + e * F + i0 + c] = f2bf(tile[c][rr]);
}

// ---------- P1: coarse-bucket histogram (256 buckets of 256 rows)
__global__ __launch_bounds__(256)
void bucket_hist(const int* __restrict__ rows, int* __restrict__ bcount, int E) {
    __shared__ int h[NB];
    const int tid = threadIdx.x;
    h[tid] = 0;
    __syncthreads();
    const int base = blockIdx.x * EPB;
    const int lim  = min(EPB, E - base);
    for (int i = tid; i < lim; i += 256)
        atomicAdd(&h[rows[base + i] >> 8], 1);
    __syncthreads();
    if (h[tid]) atomicAdd(&bcount[tid], h[tid]);
}

// ---------- P2: 256-wide exclusive scan -> bucket bases + cursors
__global__ __launch_bounds__(256)
void bucket_scan(const int* __restrict__ bcount, int* __restrict__ bbase,
                 int* __restrict__ bcursor) {
    __shared__ int s[NB];
    const int tid = threadIdx.x;
    const int c = bcount[tid];
    s[tid] = c;
    __syncthreads();
    for (int off = 1; off < NB; off <<= 1) {
        int v = (tid >= off) ? s[tid - off] : 0;
        __syncthreads();
        s[tid] += v;
        __syncthreads();
    }
    const int excl = s[tid] - c;
    bbase[tid]   = excl;
    bcursor[tid] = excl;
    if (tid == NB - 1) bbase[NB] = s[tid];
}

// ---------- P3: scatter edges into coarse buckets (L2-merged contiguous runs)
__global__ __launch_bounds__(256)
void bucket_scatter(const int* __restrict__ rows, const int* __restrict__ cols,
                    const float* __restrict__ vals, int* __restrict__ bcursor,
                    int2* __restrict__ tmp, int E) {
    __shared__ int h[NB], wb[NB];
    const int tid = threadIdx.x;
    h[tid] = 0;
    __syncthreads();
    const int base = blockIdx.x * EPB;
    const int lim  = min(EPB, E - base);
    for (int i = tid; i < lim; i += 256)
        atomicAdd(&h[rows[base + i] >> 8], 1);
    __syncthreads();
    const int c = h[tid];
    wb[tid] = c ? atomicAdd(&bcursor[tid], c) : 0;
    h[tid] = 0;
    __syncthreads();
    for (int i = tid; i < lim; i += 256) {
        const int r  = rows[base + i];
        const int bk = r >> 8;
        const int rank = atomicAdd(&h[bk], 1);
        tmp[wb[bk] + rank] = make_int2(((r & 255) << 16) | cols[base + i],
                                       __float_as_int(vals[base + i]));
    }
}

// ---------- P4: one block per bucket: exact-row sort (in place) + row offsets
__global__ __launch_bounds__(256)
void bucket_to_csr(const int* __restrict__ bbase, int2* __restrict__ tmp,
                   int* __restrict__ offsets) {
    __shared__ int2 buf[BCAP];          // 96 KB
    __shared__ int h[NB], off[NB];
    const int tid = threadIdx.x;
    const int k   = blockIdx.x;
    const int beg = bbase[k];
    const int end = bbase[k + 1];
    const int n   = end - beg;
    h[tid] = 0;
    __syncthreads();
    for (int i = tid; i < n; i += 256) {
        const int2 e = tmp[beg + i];
        if (i < BCAP) buf[i] = e;
        atomicAdd(&h[e.x >> 16], 1);
    }
    __syncthreads();
    const int c = h[tid];
    off[tid] = c;
    __syncthreads();
    for (int o = 1; o < NB; o <<= 1) {
        int v = (tid >= o) ? off[tid - o] : 0;
        __syncthreads();
        off[tid] += v;
        __syncthreads();
    }
    const int excl = off[tid] - c;
    offsets[k * NB + tid] = beg + excl;
    if (k == NB - 1 && tid == NB - 1) offsets[NN] = end;
    h[tid] = excl;                      // reuse as within-bucket cursor
    __syncthreads();
    for (int i = tid; i < n; i += 256) {
        const int2 e = (i < BCAP) ? buf[i] : tmp[beg + i];
        const int r = e.x >> 16;
        const int pos = atomicAdd(&h[r], 1);
        tmp[beg + pos] = make_int2(e.x & 0xFFFF, e.y);
    }
}

// ---------- gather: per-row segmented accumulate (fp8 x), hi written f32 into d_out
__global__ __launch_bounds__(256)
void gather_rows(const u32* __restrict__ xq, const int2* __restrict__ scv,
                 const int* __restrict__ offsets, float* __restrict__ hi) {
    const int lane = threadIdx.x & 63;
    int row = (blockIdx.x << 2) + (threadIdx.x >> 6);
    row = __builtin_amdgcn_readfirstlane(row);
    const int beg = offsets[row];
    const int end = offsets[row + 1];
    float4 acc = {0.f, 0.f, 0.f, 0.f};
    int j = beg;
    for (; j + 8 <= end; j += 8) {
        int2 cc[8];
        u32  rr[8];
        #pragma unroll
        for (int q = 0; q < 8; ++q) cc[q] = scv[j + q];
        #pragma unroll
        for (int q = 0; q < 8; ++q)
            rr[q] = (xq + (size_t)cc[q].x * (F / 4))[lane];
        #pragma unroll
        for (int q = 0; q < 8; ++q) {
            const float v = __int_as_float(cc[q].y);
            const f32x2 lo = __builtin_amdgcn_cvt_pk_f32_fp8(rr[q], false);
            const f32x2 hi2 = __builtin_amdgcn_cvt_pk_f32_fp8(rr[q], true);
            acc.x += v * lo[0];  acc.y += v * lo[1];
            acc.z += v * hi2[0]; acc.w += v * hi2[1];
        }
    }
    for (; j < end; ++j) {
        const int2 c0 = scv[j];
        const u32 r0 = (xq + (size_t)c0.x * (F / 4))[lane];
        const float v0 = __int_as_float(c0.y);
        const f32x2 lo = __builtin_amdgcn_cvt_pk_f32_fp8(r0, false);
        const f32x2 hi2 = __builtin_amdgcn_cvt_pk_f32_fp8(r0, true);
        acc.x += v0 * lo[0];  acc.y += v0 * lo[1];
        acc.z += v0 * hi2[0]; acc.w += v0 * hi2[1];
    }
    ((float4*)(hi + (size_t)row * F))[lane] = acc;
}

// ---------- GEMM: out[n,o] = sum_e z[n,e] * (hi[n,:] @ W[e]) + x[n,o]
// BK=64, 128B LDS rows with ^((row&7)<<4) swizzle (conflict-free: 8 slots
// spread 16-lane read phases 2-way max). B double-buffered via global_load_lds;
// stage(s+1) issued at step top, vmcnt(0)+s_barrier at step end (32 barriers).
// Round-10's BK=32/64B-row layout had only 4 slots -> 4-way conflicts (8.77M).
#define BM 128
__global__ __launch_bounds__(512, 1)
void moe_gemm(const float* __restrict__ hi, const float* __restrict__ z,
              const short* __restrict__ WbT, const float* __restrict__ x,
              float* __restrict__ out) {
    __shared__ short A_lds[4][BM * 64];      // 4 x 16 KB: slice i0b, rows of 128B
    __shared__ short B_lds[2][256 * 64];     // 2 x 32 KB: rows of 128B
    __shared__ float z_t[KE][BM];            // 4 KB, transposed
    const int tid  = threadIdx.x;
    const int lane = tid & 63;
    const int w    = tid >> 6;
    const int wr   = w >> 2;
    const int wc   = w & 3;
    const int row0 = blockIdx.x * BM;

    // stage B chunk s (e = s>>2, i0b = s&3) into buf: 4 x 16B per thread.
    // Linear LDS dest; source pre-swizzled by ^((o&7)<<4) within each 128B row.
    auto stageB = [&](int s, int buf) {
        const int kb0 = s * 128;
        #pragma unroll
        for (int q = 0; q < 4; ++q) {
            const int d  = (tid + q * 512) * 16;       // 0..32767
            const int o  = d >> 7;
            const int kb = d & 127;
            const char* src = (const char*)WbT + (size_t)o * (KD * 2) + kb0
                              + (kb ^ ((o & 7) << 4));
            gld_lds16((char*)&B_lds[buf][0] + d, src);
        }
    };

    stageB(0, 0);
    for (int idx = tid; idx < BM * KE; idx += 512)
        z_t[idx & 7][idx >> 3] = z[(size_t)row0 * KE + idx];
    {   // stage A: hi f32 -> bf16, slice layout + (m&7) swizzle
        const int m0 = tid >> 5;
        const int c8 = tid & 31;       // 8-float chunk: slice c8>>3, 16B slot c8&7
        for (int p = 0; p < BM / 16; ++p) {
            const int m = p * 16 + m0;
            const float4* src = (const float4*)(hi + (size_t)(row0 + m) * F + c8 * 8);
            const float4 a = src[0], b = src[1];
            short8 pk;
            pk[0]=f2bf(a.x); pk[1]=f2bf(a.y); pk[2]=f2bf(a.z); pk[3]=f2bf(a.w);
            pk[4]=f2bf(b.x); pk[5]=f2bf(b.y); pk[6]=f2bf(b.z); pk[7]=f2bf(b.w);
            const int byte = m * 128 + (((c8 & 7) * 16) ^ ((m & 7) << 4));
            *(short8*)((char*)&A_lds[c8 >> 3][0] + byte) = pk;
        }
    }
    __syncthreads();   // prologue: drains stage(0) + A/z writes

    f32x4 acc_t[4][4], acc_e[4][4];
    #pragma unroll
    for (int mi = 0; mi < 4; ++mi)
        #pragma unroll
        for (int ni = 0; ni < 4; ++ni) {
            acc_t[mi][ni] = (f32x4){0.f, 0.f, 0.f, 0.f};
            acc_e[mi][ni] = (f32x4){0.f, 0.f, 0.f, 0.f};
        }

    const int lr    = lane & 15;
    const int kq16  = (lane >> 4) * 16;    // quarter k-offset (bytes) within 64B half
    const int rbase = (lane >> 4) * 4;

    auto step = [&](int s, int cur) {
        short8 af[4][2], bf[4][2];
        #pragma unroll
        for (int ks = 0; ks < 2; ++ks) {
            const int slot = ks * 64 + kq16;
            #pragma unroll
            for (int mi = 0; mi < 4; ++mi) {
                const int m = wr * 64 + mi * 16 + lr;
                af[mi][ks] = *(const short8*)((const char*)&A_lds[s & 3][0]
                                + m * 128 + (slot ^ ((m & 7) << 4)));
            }
            #pragma unroll
            for (int ni = 0; ni < 4; ++ni) {
                const int o = wc * 64 + ni * 16 + lr;
                bf[ni][ks] = *(const short8*)((const char*)&B_lds[cur][0]
                                + o * 128 + (slot ^ ((o & 7) << 4)));
            }
        }
        #pragma unroll
        for (int ks = 0; ks < 2; ++ks)
            #pragma unroll
            for (int mi = 0; mi < 4; ++mi)
                #pragma unroll
                for (int ni = 0; ni < 4; ++ni)
                    acc_e[mi][ni] = __builtin_amdgcn_mfma_f32_16x16x32_bf16(
                        af[mi][ks], bf[ni][ks], acc_e[mi][ni], 0, 0, 0);
        if ((s & 3) == 3) {            // expert boundary: fold z, reset acc_e
            const int e = s >> 2;
            f32x4 zv[4];
            #pragma unroll
            for (int mi = 0; mi < 4; ++mi)
                zv[mi] = *(const f32x4*)&z_t[e][wr * 64 + mi * 16 + rbase];
            #pragma unroll
            for (int mi = 0; mi < 4; ++mi)
                #pragma unroll
                for (int ni = 0; ni < 4; ++ni)
                    #pragma unroll
                    for (int r = 0; r < 4; ++r) {
                        acc_t[mi][ni][r] += zv[mi][r] * acc_e[mi][ni][r];
                        acc_e[mi][ni][r] = 0.f;
                    }
        }
    };

    for (int s = 0; s < 32; ++s) {
        if (s + 1 < 32) stageB(s + 1, (s + 1) & 1);
        step(s, s & 1);
        asm volatile("s_waitcnt vmcnt(0)" ::: "memory");
        __builtin_amdgcn_s_barrier();
        __builtin_amdgcn_sched_barrier(0);
    }

    #pragma unroll
    for (int mi = 0; mi < 4; ++mi) {
        #pragma unroll
        for (int r = 0; r < 4; ++r) {
            const int m = wr * 64 + mi * 16 + rbase + r;
            const size_t rowoff = (size_t)(row0 + m) * F;
            #pragma unroll
            for (int ni = 0; ni < 4; ++ni) {
                const int o = wc * 64 + ni * 16 + lr;
                out[rowoff + o] = acc_t[mi][ni][r] + x[rowoff + o];
            }
        }
    }
}

extern "C" void kernel_launch(void* const* d_in, const int* in_sizes, int n_in,
                              void* d_out, int out_size, void* d_ws, size_t ws_size,
                              hipStream_t stream) {
    const float* x    = (const float*)d_in[0];
    // d_in[1] = h0 : unused by the reference (variant=False path)
    const float* z    = (const float*)d_in[2];
    const float* vals = (const float*)d_in[3];
    const float* W    = (const float*)d_in[4];
    const int* rows   = (const int*)d_in[5];
    const int* cols   = (const int*)d_in[6];
    float* out        = (float*)d_out;
    const int E = in_sizes[3];

    // workspace layout (~34 MB total)
    char* ws = (char*)d_ws;
    u32*   xq      = (u32*)  (ws);                               // 16 MB fp8 [NN][F]
    short* WbT     = (short*)(ws + ((size_t)16 << 20));          // 1 MB
    int*   offsets = (int*)  (ws + ((size_t)17 << 20));          // 256 KB + 4
    int*   bcount  = (int*)  (ws + ((size_t)17 << 20) + 264*1024);
    int*   bbase   = (int*)  (ws + ((size_t)17 << 20) + 266*1024);
    int*   bcursor = (int*)  (ws + ((size_t)17 << 20) + 268*1024);
    int2*  tmp     = (int2*) (ws + ((size_t)18 << 20));          // 16 MB
    float* hi      = out;    // gather output lives in d_out; moe_gemm is in-place

    const int nblk = (E + EPB - 1) / EPB;
    hipMemsetAsync(bcount, 0, NB * sizeof(int), stream);
    conv_x8<<<(NN * F) / (256 * 8), 256, 0, stream>>>(x, xq);
    prep_w<<<dim3(4, 4, 8), 256, 0, stream>>>(W, WbT);
    bucket_hist<<<nblk, 256, 0, stream>>>(rows, bcount, E);
    bucket_scan<<<1, 256, 0, stream>>>(bcount, bbase, bcursor);
    bucket_scatter<<<nblk, 256, 0, stream>>>(rows, cols, vals, bcursor, tmp, E);
    bucket_to_csr<<<NB, 256, 0, stream>>>(bbase, tmp, offsets);
    gather_rows<<<NN / 4, 256, 0, stream>>>(xq, tmp, offsets, hi);
    moe_gemm<<<NN / BM, 512, 0, stream>>>(hi, z, WbT, x, out);
}